// Round 12
// baseline (561.928 us; speedup 1.0000x reference)
//
#include <hip/hip_runtime.h>
#include <hip/hip_bf16.h>

#define N_NODES 20000
#define N_EDGES 160000
#define DIN_NODE 256
#define DIN_EDGE 64
#define DF 128      // feature dim
#define HH 256      // edge-MLP hidden dim
#define TT 17       // node types
#define NE_PAD_SLOTS 20544   // 642 blocks * 32 (type-padded bucket list)
#define NB_NODE (NE_PAD_SLOTS / 32)   // 642 node-embed blocks

typedef __attribute__((ext_vector_type(8))) short short8v;   // 8 bf16
typedef __attribute__((ext_vector_type(4))) float f32x4;     // MFMA C/D frag

// fp32 -> bf16 round-to-nearest-even
__device__ __forceinline__ unsigned short f2bf(float f) {
  unsigned int u = __builtin_bit_cast(unsigned int, f);
  u += 0x7FFFu + ((u >> 16) & 1u);
  return (unsigned short)(u >> 16);
}

__device__ __forceinline__ float bf2f(unsigned short u) {
  return __builtin_bit_cast(float, (unsigned int)u << 16);
}

__device__ __forceinline__ short8v pack8(float4 a, float4 b) {
  short8v o;
  o[0] = (short)f2bf(a.x); o[1] = (short)f2bf(a.y);
  o[2] = (short)f2bf(a.z); o[3] = (short)f2bf(a.w);
  o[4] = (short)f2bf(b.x); o[5] = (short)f2bf(b.y);
  o[6] = (short)f2bf(b.z); o[7] = (short)f2bf(b.w);
  return o;
}

// ---------------------------------------------------------------------------
// Pack ALL weights in one dispatch.  2320 tiles total, 4 tiles/block.
// ---------------------------------------------------------------------------
struct PackPtrs {
  const float *s0, *s1, *s2, *s3, *s4, *s5, *s6, *s7, *s8, *s9, *s10, *s11;
  unsigned short *d0, *d1, *d2, *d3, *d4, *d5, *d6, *d7, *d8, *d9, *d10, *d11;
};

__global__ __launch_bounds__(256) void k_pack_all(PackPtrs P) {
  const int g = blockIdx.x * 4 + (threadIdx.x >> 6);
  const int l = threadIdx.x & 63;
  if (g >= 2320) return;
  const float* w; unsigned short* out; int K, N, tile;
  if (g < 128)       { w = P.s0;  out = P.d0;  K = 256; N = 256; tile = g; }
  else if (g < 256)  { w = P.s1;  out = P.d1;  K = 256; N = 256; tile = g - 128; }
  else if (g < 384)  { w = P.s2;  out = P.d2;  K = 256; N = 256; tile = g - 256; }
  else if (g < 448)  { w = P.s3;  out = P.d3;  K = 256; N = 128; tile = g - 384; }
  else if (g < 544)  { w = P.s4;  out = P.d4;  K = 384; N = 128; tile = g - 448; }
  else if (g < 1632) { w = P.s5;  out = P.d5;  K = 256; N = 128; tile = g - 544; }
  else if (g < 2176) { w = P.s6;  out = P.d6;  K = 128; N = 128; tile = g - 1632; }
  else if (g < 2192) { w = P.s7;  out = P.d7;  K = 64;  N = 128; tile = g - 2176; }
  else if (g < 2224) { w = P.s8;  out = P.d8;  K = 128; N = 128; tile = g - 2192; }
  else if (g < 2256) { w = P.s9;  out = P.d9;  K = 128; N = 128; tile = g - 2224; }
  else if (g < 2288) { w = P.s10; out = P.d10; K = 128; N = 128; tile = g - 2256; }
  else               { w = P.s11; out = P.d11; K = 128; N = 128; tile = g - 2288; }
  const int ntTiles = N >> 4;
  const int tilesPer = (K >> 5) * ntTiles;
  const int bt = tile / tilesPer;
  const int rr = tile - bt * tilesPer;
  const int kt = rr / ntTiles, nt = rr - kt * ntTiles;
  const float* wb = w + (size_t)bt * K * N;
  const int col = (nt << 4) + (l & 15);
  const int k0 = (kt << 5) + ((l >> 4) << 3);
  unsigned short* o = out + (((size_t)tile << 6) + l) * 8;
#pragma unroll
  for (int j = 0; j < 8; ++j) o[j] = f2bf(wb[(size_t)(k0 + j) * N + col]);
}

// ---------------------------------------------------------------------------
// Setup: merged count (node types + dst degree), merged scans, merged scatter.
// ---------------------------------------------------------------------------
__global__ void k_count_deg(const int* __restrict__ types,
                            const int* __restrict__ dstv,
                            int* __restrict__ cnt, int* __restrict__ deg) {
  const int i = blockIdx.x * 256 + threadIdx.x;
  if (i < N_NODES) atomicAdd(&cnt[types[i]], 1);
  if (i < N_EDGES) atomicAdd(&deg[dstv[i]], 1);
}

__global__ __launch_bounds__(1024) void k_prefix_scan(
    const int* __restrict__ cnt, int* __restrict__ woff,
    const int* __restrict__ deg, int* __restrict__ rs, int* __restrict__ wo) {
  __shared__ int partial[1024];
  const int t = threadIdx.x;
  if (t == 0) {
    int cur = 0;
    for (int ty = 0; ty < TT; ++ty) {
      woff[ty] = cur;
      cur += (cnt[ty] + 31) & ~31;
    }
  }
  const int base = t * 20;
  int s = 0;
  for (int j = 0; j < 20; ++j) {
    const int n = base + j;
    if (n < N_NODES) s += deg[n];
  }
  partial[t] = s;
  __syncthreads();
  for (int off = 1; off < 1024; off <<= 1) {
    const int v = (t >= off) ? partial[t - off] : 0;
    __syncthreads();
    partial[t] += v;
    __syncthreads();
  }
  int run = (t > 0) ? partial[t - 1] : 0;
  for (int j = 0; j < 20; ++j) {
    const int n = base + j;
    if (n < N_NODES) {
      rs[n] = run; wo[n] = run;
      run += deg[n];
    }
  }
  if (t == 1023) rs[N_NODES] = run;
}

__global__ void k_scatter_elist(const int* __restrict__ types,
                                const int* __restrict__ srcv,
                                const int* __restrict__ dstv,
                                int* __restrict__ woff, int* __restrict__ wo,
                                int* __restrict__ bucket,
                                int* __restrict__ elist, int* __restrict__ ipos,
                                int* __restrict__ srcp, int* __restrict__ dstp) {
  const int i = blockIdx.x * 256 + threadIdx.x;
  if (i < N_NODES) {
    const int pos = atomicAdd(&woff[types[i]], 1);
    bucket[pos] = i;
  }
  if (i < N_EDGES) {
    const int pos = atomicAdd(&wo[dstv[i]], 1);
    elist[pos] = i;
    ipos[i] = pos;
    srcp[pos] = srcv[i];
    dstp[pos] = dstv[i];
  }
}

// ---------------------------------------------------------------------------
// Fused embedding dispatch (unchanged from R11, passing).
// ---------------------------------------------------------------------------
__global__ __launch_bounds__(256) void k_embed_fused(
    const float* __restrict__ x, const int* __restrict__ bucket,
    const int* __restrict__ types,
    const unsigned short* __restrict__ wp1, const float* __restrict__ b1,
    const unsigned short* __restrict__ wp2, const float* __restrict__ b2,
    unsigned short* __restrict__ nf0b,
    const unsigned short* __restrict__ wpd, const unsigned short* __restrict__ wps,
    unsigned short* __restrict__ PDo, unsigned short* __restrict__ PSo,
    const float* __restrict__ ea, const int* __restrict__ ipos,
    const unsigned short* __restrict__ ewp1, const float* __restrict__ eb1,
    const unsigned short* __restrict__ ewp2, const float* __restrict__ eb2,
    unsigned short* __restrict__ ef0p) {
  __shared__ __align__(16) unsigned char A[32 * 512];   // 16 KB
  __shared__ __align__(16) unsigned char Hb[32 * 256];  // 8 KB
  __shared__ int sidx[32];
  const int t = threadIdx.x;
  const int w = t >> 6, l = t & 63, lr = l & 15, lg = l >> 4;
  const int sw = (lr & 7) << 4;
  const int row0 = lr, row1 = 16 + lr;

  if (blockIdx.x < NB_NODE) {
    // ================= node path =================
    const int r0 = blockIdx.x * 32;
    if (t < 32) sidx[t] = bucket[r0 + t];
    __syncthreads();
    if (sidx[0] < 0) return;
    const int ty = types[sidx[0]];

#pragma unroll
    for (int j = 0; j < 4; ++j) {
      const int q = j * 256 + t;
      const int i = q >> 5, c = q & 31;
      const int nd = sidx[i];
      short8v o;
      if (nd >= 0) {
        const float* xr = x + (size_t)nd * DIN_NODE + c * 8;
        o = pack8(*reinterpret_cast<const float4*>(xr),
                  *reinterpret_cast<const float4*>(xr + 4));
      } else {
#pragma unroll
        for (int k = 0; k < 8; ++k) o[k] = 0;
      }
      *reinterpret_cast<short8v*>(A + ((i * 512 + c * 16) ^ ((i & 7) << 4))) = o;
    }
    __syncthreads();

    f32x4 acc[2][2];
#pragma unroll
    for (int mt = 0; mt < 2; ++mt)
#pragma unroll
      for (int q = 0; q < 2; ++q)
#pragma unroll
        for (int r = 0; r < 4; ++r) acc[mt][q][r] = 0.f;
#pragma unroll
    for (int kt = 0; kt < 8; ++kt) {
      const short8v a0 = *reinterpret_cast<const short8v*>(
          A + ((row0 * 512 + kt * 64 + lg * 16) ^ sw));
      const short8v a1 = *reinterpret_cast<const short8v*>(
          A + ((row1 * 512 + kt * 64 + lg * 16) ^ sw));
#pragma unroll
      for (int q = 0; q < 2; ++q) {
        const short8v bq = *reinterpret_cast<const short8v*>(
            wp1 + (((size_t)(ty * 64 + kt * 8 + 2 * w + q) * 64 + l) << 3));
        acc[0][q] = __builtin_amdgcn_mfma_f32_16x16x32_bf16(a0, bq, acc[0][q], 0, 0, 0);
        acc[1][q] = __builtin_amdgcn_mfma_f32_16x16x32_bf16(a1, bq, acc[1][q], 0, 0, 0);
      }
    }
#pragma unroll
    for (int q = 0; q < 2; ++q) {
      const int col = (2 * w + q) * 16 + lr;
      const float bias = b1[ty * DF + col];
#pragma unroll
      for (int mt = 0; mt < 2; ++mt)
#pragma unroll
        for (int r = 0; r < 4; ++r) {
          const int row = mt * 16 + lg * 4 + r;
          *reinterpret_cast<unsigned short*>(
              Hb + ((row * 256 + col * 2) ^ ((row & 7) << 4))) =
              f2bf(fmaxf(acc[mt][q][r] + bias, 0.f));
        }
    }
    __syncthreads();

    f32x4 acc2[2][2];
#pragma unroll
    for (int mt = 0; mt < 2; ++mt)
#pragma unroll
      for (int q = 0; q < 2; ++q)
#pragma unroll
        for (int r = 0; r < 4; ++r) acc2[mt][q][r] = 0.f;
#pragma unroll
    for (int kt = 0; kt < 4; ++kt) {
      const short8v a0 = *reinterpret_cast<const short8v*>(
          Hb + ((row0 * 256 + kt * 64 + lg * 16) ^ sw));
      const short8v a1 = *reinterpret_cast<const short8v*>(
          Hb + ((row1 * 256 + kt * 64 + lg * 16) ^ sw));
#pragma unroll
      for (int q = 0; q < 2; ++q) {
        const short8v bq = *reinterpret_cast<const short8v*>(
            wp2 + (((size_t)(ty * 32 + kt * 8 + 2 * w + q) * 64 + l) << 3));
        acc2[0][q] = __builtin_amdgcn_mfma_f32_16x16x32_bf16(a0, bq, acc2[0][q], 0, 0, 0);
        acc2[1][q] = __builtin_amdgcn_mfma_f32_16x16x32_bf16(a1, bq, acc2[1][q], 0, 0, 0);
      }
    }
    // write nf0 to global AND into A as [nf0|nf0] for the fused partial
#pragma unroll
    for (int q = 0; q < 2; ++q) {
      const int col = (2 * w + q) * 16 + lr;
      const float bias = b2[ty * DF + col];
#pragma unroll
      for (int mt = 0; mt < 2; ++mt)
#pragma unroll
        for (int r = 0; r < 4; ++r) {
          const int row = mt * 16 + lg * 4 + r;
          const int nd = sidx[row];
          const unsigned short v = f2bf(acc2[mt][q][r] + bias);
          if (nd >= 0) nf0b[(size_t)nd * DF + col] = v;
          *reinterpret_cast<unsigned short*>(
              A + ((row * 512 + col * 2) ^ ((row & 7) << 4))) = v;
          *reinterpret_cast<unsigned short*>(
              A + ((row * 512 + (col + 128) * 2) ^ ((row & 7) << 4))) = v;
        }
    }
    __syncthreads();

    // fused step-1 partials: PD/PS = [nf0|nf0] @ wpd/wps (K=256)
    f32x4 aD[2][4], aS[2][4];
#pragma unroll
    for (int mt = 0; mt < 2; ++mt)
#pragma unroll
      for (int q = 0; q < 4; ++q)
#pragma unroll
        for (int r = 0; r < 4; ++r) { aD[mt][q][r] = 0.f; aS[mt][q][r] = 0.f; }
    const int r0o = lr * 512 + lg * 16, r1o = (16 + lr) * 512 + lg * 16;
#pragma unroll
    for (int kt = 0; kt < 8; ++kt) {
      const short8v a0 = *reinterpret_cast<const short8v*>(A + ((r0o + kt * 64) ^ sw));
      const short8v a1 = *reinterpret_cast<const short8v*>(A + ((r1o + kt * 64) ^ sw));
#pragma unroll
      for (int q = 0; q < 4; ++q) {
        const size_t bi = (((size_t)(kt * 16 + 4 * w + q) * 64 + l) << 3);
        const short8v bD = *reinterpret_cast<const short8v*>(wpd + bi);
        const short8v bS = *reinterpret_cast<const short8v*>(wps + bi);
        aD[0][q] = __builtin_amdgcn_mfma_f32_16x16x32_bf16(a0, bD, aD[0][q], 0, 0, 0);
        aD[1][q] = __builtin_amdgcn_mfma_f32_16x16x32_bf16(a1, bD, aD[1][q], 0, 0, 0);
        aS[0][q] = __builtin_amdgcn_mfma_f32_16x16x32_bf16(a0, bS, aS[0][q], 0, 0, 0);
        aS[1][q] = __builtin_amdgcn_mfma_f32_16x16x32_bf16(a1, bS, aS[1][q], 0, 0, 0);
      }
    }
#pragma unroll
    for (int q = 0; q < 4; ++q) {
      const int col = (4 * w + q) * 16 + lr;
#pragma unroll
      for (int mt = 0; mt < 2; ++mt)
#pragma unroll
        for (int r = 0; r < 4; ++r) {
          const int row = mt * 16 + lg * 4 + r;
          const int nd = sidx[row];
          if (nd >= 0) {
            PDo[(size_t)nd * HH + col] = f2bf(aD[mt][q][r]);
            PSo[(size_t)nd * HH + col] = f2bf(aS[mt][q][r]);
          }
        }
    }
  } else {
    // ================= edge path =================
    const int e0 = (blockIdx.x - NB_NODE) * 32;
    if (t < 32) sidx[t] = ipos[e0 + t];
    {
      const int i = t >> 3, c = t & 7;
      const float* xr = ea + (size_t)(e0 + i) * DIN_EDGE + c * 8;
      const short8v o = pack8(*reinterpret_cast<const float4*>(xr),
                              *reinterpret_cast<const float4*>(xr + 4));
      *reinterpret_cast<short8v*>(A + ((i * 128 + c * 16) ^ ((i & 7) << 4))) = o;
    }
    __syncthreads();

    f32x4 acc[2][2];
#pragma unroll
    for (int mt = 0; mt < 2; ++mt)
#pragma unroll
      for (int q = 0; q < 2; ++q)
#pragma unroll
        for (int r = 0; r < 4; ++r) acc[mt][q][r] = 0.f;
#pragma unroll
    for (int kt = 0; kt < 2; ++kt) {
      const short8v a0 = *reinterpret_cast<const short8v*>(
          A + ((row0 * 128 + kt * 64 + lg * 16) ^ sw));
      const short8v a1 = *reinterpret_cast<const short8v*>(
          A + ((row1 * 128 + kt * 64 + lg * 16) ^ sw));
#pragma unroll
      for (int q = 0; q < 2; ++q) {
        const short8v bq = *reinterpret_cast<const short8v*>(
            ewp1 + (((size_t)(kt * 8 + 2 * w + q) * 64 + l) << 3));
        acc[0][q] = __builtin_amdgcn_mfma_f32_16x16x32_bf16(a0, bq, acc[0][q], 0, 0, 0);
        acc[1][q] = __builtin_amdgcn_mfma_f32_16x16x32_bf16(a1, bq, acc[1][q], 0, 0, 0);
      }
    }
#pragma unroll
    for (int q = 0; q < 2; ++q) {
      const int col = (2 * w + q) * 16 + lr;
      const float bias = eb1[col];
#pragma unroll
      for (int mt = 0; mt < 2; ++mt)
#pragma unroll
        for (int r = 0; r < 4; ++r) {
          const int row = mt * 16 + lg * 4 + r;
          *reinterpret_cast<unsigned short*>(
              Hb + ((row * 256 + col * 2) ^ ((row & 7) << 4))) =
              f2bf(fmaxf(acc[mt][q][r] + bias, 0.f));
        }
    }
    __syncthreads();

    f32x4 acc2[2][2];
#pragma unroll
    for (int mt = 0; mt < 2; ++mt)
#pragma unroll
      for (int q = 0; q < 2; ++q)
#pragma unroll
        for (int r = 0; r < 4; ++r) acc2[mt][q][r] = 0.f;
#pragma unroll
    for (int kt = 0; kt < 4; ++kt) {
      const short8v a0 = *reinterpret_cast<const short8v*>(
          Hb + ((row0 * 256 + kt * 64 + lg * 16) ^ sw));
      const short8v a1 = *reinterpret_cast<const short8v*>(
          Hb + ((row1 * 256 + kt * 64 + lg * 16) ^ sw));
#pragma unroll
      for (int q = 0; q < 2; ++q) {
        const short8v bq = *reinterpret_cast<const short8v*>(
            ewp2 + (((size_t)(kt * 8 + 2 * w + q) * 64 + l) << 3));
        acc2[0][q] = __builtin_amdgcn_mfma_f32_16x16x32_bf16(a0, bq, acc2[0][q], 0, 0, 0);
        acc2[1][q] = __builtin_amdgcn_mfma_f32_16x16x32_bf16(a1, bq, acc2[1][q], 0, 0, 0);
      }
    }
#pragma unroll
    for (int q = 0; q < 2; ++q) {
      const int col = (2 * w + q) * 16 + lr;
      const float bias = eb2[col];
#pragma unroll
      for (int mt = 0; mt < 2; ++mt)
#pragma unroll
        for (int r = 0; r < 4; ++r) {
          const int row = mt * 16 + lg * 4 + r;
          ef0p[(size_t)sidx[row] * DF + col] = f2bf(acc2[mt][q][r] + bias);
        }
    }
  }
}

// ---------------------------------------------------------------------------
// Edge MLP v10: exactly 32 KB LDS for non-HEAD variants (se removed, hpart
// conditional) -> 5 blocks/CU target.  Otherwise identical to v9 (passing).
// ---------------------------------------------------------------------------
template <bool OUTF, bool HEAD>
__global__ __launch_bounds__(256, 5) void k_edge_mlp_mfma(
    const unsigned short* __restrict__ ef0, const unsigned short* __restrict__ ef_in,
    unsigned short* __restrict__ ef_out, float* __restrict__ ef_outf,
    const int* __restrict__ srcp, const int* __restrict__ dstp,
    const int* __restrict__ elist,
    const unsigned short* __restrict__ wpe, const float* __restrict__ b1,
    const unsigned short* __restrict__ wp2, const float* __restrict__ b2,
    const unsigned short* __restrict__ PDi, const unsigned short* __restrict__ PSi,
    const unsigned short* __restrict__ wech, const float* __restrict__ hb1,
    const float* __restrict__ hw2, const float* __restrict__ hb2,
    float* __restrict__ out_pe) {
  __shared__ __align__(16) unsigned char A_lds[32 * 512];  // [ef0|ef] 16 KB
  __shared__ __align__(16) unsigned char P_lds[32 * 512];  // Pre / hidden 16 KB
  const int t = threadIdx.x;
  const int e0 = blockIdx.x * 32;

  // ---- issue A loads and Pre loads together (one overlapped round trip) ----
  short8v av[4], pdv[4], psv[4];
#pragma unroll
  for (int j = 0; j < 4; ++j) {
    const int q = j * 256 + t;
    const int i = q >> 5, c = q & 31;
    const unsigned short* bp = (c < 16)
        ? ef0 + (size_t)(e0 + i) * DF + c * 8
        : ef_in + (size_t)(e0 + i) * DF + (c - 16) * 8;
    av[j] = *reinterpret_cast<const short8v*>(bp);
  }
#pragma unroll
  for (int j = 0; j < 4; ++j) {
    const int q = j * 256 + t;
    const int i = q >> 5, c = q & 31;
    const int dn = dstp[e0 + i];
    const int sn = srcp[e0 + i];
    pdv[j] = *reinterpret_cast<const short8v*>(PDi + (size_t)dn * HH + c * 8);
    psv[j] = *reinterpret_cast<const short8v*>(PSi + (size_t)sn * HH + c * 8);
  }
  // write both LDS buffers
#pragma unroll
  for (int j = 0; j < 4; ++j) {
    const int q = j * 256 + t;
    const int i = q >> 5, c = q & 31;
    const int off = (i * 512 + c * 16) ^ ((i & 7) << 4);
    *reinterpret_cast<short8v*>(A_lds + off) = av[j];
    short8v o;
#pragma unroll
    for (int k = 0; k < 8; ++k)
      o[k] = (short)f2bf(bf2f((unsigned short)pdv[j][k]) +
                         bf2f((unsigned short)psv[j][k]));
    *reinterpret_cast<short8v*>(P_lds + off) = o;
  }
  __syncthreads();

  const int w = t >> 6, l = t & 63, lr = l & 15, lg = l >> 4;
  const int swz = (lr & 7) << 4;

  // ---- layer 1: acc init from Pre, then [32x256]@[256x256] ----------------
  f32x4 acc[2][4];
#pragma unroll
  for (int mt = 0; mt < 2; ++mt)
#pragma unroll
    for (int q = 0; q < 4; ++q) {
      const int col = (4 * w + q) * 16 + lr;
#pragma unroll
      for (int r = 0; r < 4; ++r) {
        const int row = mt * 16 + lg * 4 + r;
        const unsigned short u = *reinterpret_cast<const unsigned short*>(
            P_lds + ((row * 512 + col * 2) ^ ((row & 7) << 4)));
        acc[mt][q][r] = bf2f(u);
      }
    }

  const int r0o = lr * 512 + lg * 16;
  const int r1o = (16 + lr) * 512 + lg * 16;
  const unsigned short* wb1 = wpe + (((size_t)(4 * w) * 64 + l) << 3);

  short8v aR[3][2], bR[3][4];
#pragma unroll
  for (int s = 0; s < 2; ++s) {
    aR[s][0] = *reinterpret_cast<const short8v*>(A_lds + ((r0o + s * 64) ^ swz));
    aR[s][1] = *reinterpret_cast<const short8v*>(A_lds + ((r1o + s * 64) ^ swz));
#pragma unroll
    for (int q = 0; q < 4; ++q)
      bR[s][q] = *reinterpret_cast<const short8v*>(wb1 + (size_t)s * 8192 + q * 512);
  }
#pragma unroll
  for (int kt = 0; kt < 8; ++kt) {
    const int cur = kt % 3, pf = (kt + 2) % 3;
    if (kt < 6) {
      aR[pf][0] = *reinterpret_cast<const short8v*>(
          A_lds + ((r0o + (kt + 2) * 64) ^ swz));
      aR[pf][1] = *reinterpret_cast<const short8v*>(
          A_lds + ((r1o + (kt + 2) * 64) ^ swz));
#pragma unroll
      for (int q = 0; q < 4; ++q)
        bR[pf][q] = *reinterpret_cast<const short8v*>(
            wb1 + (size_t)(kt + 2) * 8192 + q * 512);
    }
#pragma unroll
    for (int q = 0; q < 4; ++q) {
      acc[0][q] = __builtin_amdgcn_mfma_f32_16x16x32_bf16(aR[cur][0], bR[cur][q],
                                                          acc[0][q], 0, 0, 0);
      acc[1][q] = __builtin_amdgcn_mfma_f32_16x16x32_bf16(aR[cur][1], bR[cur][q],
                                                          acc[1][q], 0, 0, 0);
    }
  }
  __syncthreads();   // done reading A_lds and P_lds

  // hidden (bias+relu) -> bf16 [32][256], overwrites P_lds
#pragma unroll
  for (int q = 0; q < 4; ++q) {
    const int col = (4 * w + q) * 16 + lr;
    const float bias = b1[col];
#pragma unroll
    for (int mt = 0; mt < 2; ++mt)
#pragma unroll
      for (int r = 0; r < 4; ++r) {
        const int row = mt * 16 + lg * 4 + r;
        *reinterpret_cast<unsigned short*>(
            P_lds + ((row * 512 + col * 2) ^ ((row & 7) << 4))) =
            f2bf(fmaxf(acc[mt][q][r] + bias, 0.f));
      }
  }
  __syncthreads();

  // ---- layer 2: [32x256] @ [256x128] ---------------------------------------
  f32x4 acc2[2][2];
#pragma unroll
  for (int mt = 0; mt < 2; ++mt)
#pragma unroll
    for (int q = 0; q < 2; ++q)
#pragma unroll
      for (int r = 0; r < 4; ++r) acc2[mt][q][r] = 0.f;

  const int h0o = lr * 512 + lg * 16;
  const int h1o = (16 + lr) * 512 + lg * 16;
  const unsigned short* wb2 = wp2 + (((size_t)(2 * w) * 64 + l) << 3);

  short8v aS[3][2], bS[3][2];
#pragma unroll
  for (int s = 0; s < 2; ++s) {
    aS[s][0] = *reinterpret_cast<const short8v*>(P_lds + ((h0o + s * 64) ^ swz));
    aS[s][1] = *reinterpret_cast<const short8v*>(P_lds + ((h1o + s * 64) ^ swz));
#pragma unroll
    for (int q = 0; q < 2; ++q)
      bS[s][q] = *reinterpret_cast<const short8v*>(wb2 + (size_t)s * 4096 + q * 512);
  }
#pragma unroll
  for (int kt = 0; kt < 8; ++kt) {
    const int cur = kt % 3, pf = (kt + 2) % 3;
    if (kt < 6) {
      aS[pf][0] = *reinterpret_cast<const short8v*>(
          P_lds + ((h0o + (kt + 2) * 64) ^ swz));
      aS[pf][1] = *reinterpret_cast<const short8v*>(
          P_lds + ((h1o + (kt + 2) * 64) ^ swz));
#pragma unroll
      for (int q = 0; q < 2; ++q)
        bS[pf][q] = *reinterpret_cast<const short8v*>(
            wb2 + (size_t)(kt + 2) * 4096 + q * 512);
    }
#pragma unroll
    for (int q = 0; q < 2; ++q) {
      acc2[0][q] = __builtin_amdgcn_mfma_f32_16x16x32_bf16(aS[cur][0], bS[cur][q],
                                                           acc2[0][q], 0, 0, 0);
      acc2[1][q] = __builtin_amdgcn_mfma_f32_16x16x32_bf16(aS[cur][1], bS[cur][q],
                                                           acc2[1][q], 0, 0, 0);
    }
  }

  // ---- epilogue: bias, store e_new (permuted bf16; + fp32 scatter if OUTF) --
  int seL[2][4];
  if constexpr (OUTF) {
#pragma unroll
    for (int mt = 0; mt < 2; ++mt)
#pragma unroll
      for (int r = 0; r < 4; ++r)
        seL[mt][r] = elist[e0 + mt * 16 + lg * 4 + r];
  }
#pragma unroll
  for (int q = 0; q < 2; ++q) {
    const int n = (2 * w + q) * 16 + lr;
    const float bias = b2[n];
#pragma unroll
    for (int mt = 0; mt < 2; ++mt)
#pragma unroll
      for (int r = 0; r < 4; ++r) {
        const int m = mt * 16 + lg * 4 + r;
        const float v = acc2[mt][q][r] + bias;
        ef_out[(size_t)(e0 + m) * DF + n] = f2bf(v);
        if (OUTF)
          ef_outf[(size_t)seL[mt][r] * DF + n] = v;
      }
  }

  // ---- fused edge classifier head (step 2 only) ----------------------------
  if constexpr (HEAD) {
    __shared__ float hpart[32][8];
    __syncthreads();   // all layer-2 reads of P_lds done
#pragma unroll
    for (int q = 0; q < 2; ++q) {
      const int n = (2 * w + q) * 16 + lr;
      const float bias = b2[n];
#pragma unroll
      for (int mt = 0; mt < 2; ++mt)
#pragma unroll
        for (int r = 0; r < 4; ++r) {
          const int m = mt * 16 + lg * 4 + r;
          *reinterpret_cast<unsigned short*>(
              P_lds + ((m * 256 + n * 2) ^ ((m & 7) << 4))) =
              f2bf(acc2[mt][q][r] + bias);
        }
    }
    __syncthreads();
    f32x4 ah[2][2];
#pragma unroll
    for (int mt = 0; mt < 2; ++mt)
#pragma unroll
      for (int q = 0; q < 2; ++q)
#pragma unroll
        for (int r = 0; r < 4; ++r) ah[mt][q][r] = 0.f;
#pragma unroll
    for (int kt = 0; kt < 4; ++kt) {
      const short8v a0 = *reinterpret_cast<const short8v*>(
          P_lds + ((lr * 256 + kt * 64 + lg * 16) ^ swz));
      const short8v a1 = *reinterpret_cast<const short8v*>(
          P_lds + (((16 + lr) * 256 + kt * 64 + lg * 16) ^ swz));
#pragma unroll
      for (int q = 0; q < 2; ++q) {
        const short8v bq = *reinterpret_cast<const short8v*>(
            wech + (((size_t)(kt * 8 + 2 * w + q) * 64 + l) << 3));
        ah[0][q] = __builtin_amdgcn_mfma_f32_16x16x32_bf16(a0, bq, ah[0][q], 0, 0, 0);
        ah[1][q] = __builtin_amdgcn_mfma_f32_16x16x32_bf16(a1, bq, ah[1][q], 0, 0, 0);
      }
    }
#pragma unroll
    for (int q = 0; q < 2; ++q) {
      const int col = (2 * w + q) * 16 + lr;
      const float bias = hb1[col];
#pragma unroll
      for (int mt = 0; mt < 2; ++mt)
#pragma unroll
        for (int r = 0; r < 4; ++r) {
          const int row = mt * 16 + lg * 4 + r;
          *reinterpret_cast<unsigned short*>(A_lds + row * 256 + col * 2) =
              f2bf(fmaxf(ah[mt][q][r] + bias, 0.f));
        }
    }
    __syncthreads();
    {
      const int rr = t >> 3, kc = t & 7;
      float s = 0.f;
#pragma unroll
      for (int u = 0; u < 16; ++u)
        s = fmaf(bf2f(*reinterpret_cast<const unsigned short*>(
                     A_lds + rr * 256 + (kc * 16 + u) * 2)),
                 hw2[kc * 16 + u], s);
      hpart[rr][kc] = s;
    }
    __syncthreads();
    if (t < 32) {
      float s = hb2[0];
#pragma unroll
      for (int k = 0; k < 8; ++k) s += hpart[t][k];
      out_pe[elist[e0 + t]] = s;
    }
  }
}

// ---------------------------------------------------------------------------
// Node update: CONTIGUOUS CSR gather + fused PART (steps 1-2) or fused node
// heads (HEADS, step 3).
// ---------------------------------------------------------------------------
template <bool OUTF, bool PART, bool HEADS>
__global__ __launch_bounds__(256) void k_node_update_mfma(
    const unsigned short* __restrict__ nf0, const unsigned short* __restrict__ nfb,
    const unsigned short* __restrict__ efp,
    const int* __restrict__ rs, void* __restrict__ outp,
    const unsigned short* __restrict__ wp, const float* __restrict__ b,
    const unsigned short* __restrict__ wpd, const unsigned short* __restrict__ wps,
    unsigned short* __restrict__ PDo, unsigned short* __restrict__ PSo,
    const unsigned short* __restrict__ wpn, const float* __restrict__ nb1,
    const float* __restrict__ nw2, const float* __restrict__ nb2,
    const unsigned short* __restrict__ wpc, const float* __restrict__ cb1,
    const float* __restrict__ cw2, const float* __restrict__ cb2,
    float* __restrict__ out_pn, float* __restrict__ out_pc) {
  __shared__ __align__(16) unsigned char A[32 * 768];   // 32 x 384 bf16, 24 KB
  const int t = threadIdx.x;
  const int n0 = blockIdx.x * 32;
#pragma unroll
  for (int j = 0; j < 4; ++j) {
    const int q = j * 256 + t;
    const int i = q >> 5, c = q & 31;
    const unsigned short* bp = (c < 16)
        ? nf0 + (size_t)(n0 + i) * DF + c * 8
        : nfb + (size_t)(n0 + i) * DF + (c - 16) * 8;
    *reinterpret_cast<short8v*>(A + ((i * 768 + c * 16) ^ ((i & 7) << 4))) =
        *reinterpret_cast<const short8v*>(bp);
  }
  // CSR aggregation into part 2: 8 threads/node, 16 dims each, CONTIGUOUS rows
  {
    const int i = t >> 3, sub = t & 7;
    const int n = n0 + i;
    const int kb = rs[n], ke = rs[n + 1];
    float av[16];
#pragma unroll
    for (int u = 0; u < 16; ++u) av[u] = 0.f;
    for (int k = kb; k < ke; ++k) {
      const unsigned short* er = efp + (size_t)k * DF + sub * 16;
      const short8v v0 = *reinterpret_cast<const short8v*>(er);
      const short8v v1 = *reinterpret_cast<const short8v*>(er + 8);
#pragma unroll
      for (int u = 0; u < 8; ++u) {
        av[u] += bf2f((unsigned short)v0[u]);
        av[8 + u] += bf2f((unsigned short)v1[u]);
      }
    }
    short8v o0, o1;
#pragma unroll
    for (int u = 0; u < 8; ++u) {
      o0[u] = (short)f2bf(av[u]);
      o1[u] = (short)f2bf(av[8 + u]);
    }
    const int c0 = 32 + sub * 2;
    *reinterpret_cast<short8v*>(A + ((i * 768 + c0 * 16) ^ ((i & 7) << 4))) = o0;
    *reinterpret_cast<short8v*>(A + ((i * 768 + (c0 + 1) * 16) ^ ((i & 7) << 4))) = o1;
  }
  __syncthreads();

  const int w = t >> 6, l = t & 63, lr = l & 15, lg = l >> 4;
  const int sw = (lr & 7) << 4;
  const int row0 = lr, row1 = 16 + lr;

  f32x4 acc[2][2];
#pragma unroll
  for (int mt = 0; mt < 2; ++mt)
#pragma unroll
    for (int q = 0; q < 2; ++q)
#pragma unroll
      for (int r = 0; r < 4; ++r) acc[mt][q][r] = 0.f;
#pragma unroll
  for (int kt = 0; kt < 12; ++kt) {
    const short8v a0 = *reinterpret_cast<const short8v*>(
        A + ((row0 * 768 + kt * 64 + lg * 16) ^ sw));
    const short8v a1 = *reinterpret_cast<const short8v*>(
        A + ((row1 * 768 + kt * 64 + lg * 16) ^ sw));
#pragma unroll
    for (int q = 0; q < 2; ++q) {
      const short8v bq = *reinterpret_cast<const short8v*>(
          wp + (((size_t)(kt * 8 + 2 * w + q) * 64 + l) << 3));
      acc[0][q] = __builtin_amdgcn_mfma_f32_16x16x32_bf16(a0, bq, acc[0][q], 0, 0, 0);
      acc[1][q] = __builtin_amdgcn_mfma_f32_16x16x32_bf16(a1, bq, acc[1][q], 0, 0, 0);
    }
  }
#pragma unroll
  for (int q = 0; q < 2; ++q) {
    const int col = (2 * w + q) * 16 + lr;
    const float bias = b[col];
#pragma unroll
    for (int mt = 0; mt < 2; ++mt)
#pragma unroll
      for (int r = 0; r < 4; ++r) {
        const int row = mt * 16 + lg * 4 + r;
        const float v = acc[mt][q][r] + bias;
        if (OUTF)
          ((float*)outp)[(size_t)(n0 + row) * DF + col] = v;
        else
          ((unsigned short*)outp)[(size_t)(n0 + row) * DF + col] = f2bf(v);
      }
  }

  if constexpr (PART) {
    __syncthreads();   // all MFMA reads of A done
#pragma unroll
    for (int q = 0; q < 2; ++q) {
      const int col = (2 * w + q) * 16 + lr;
      const float bias = b[col];
#pragma unroll
      for (int mt = 0; mt < 2; ++mt)
#pragma unroll
        for (int r = 0; r < 4; ++r) {
          const int row = mt * 16 + lg * 4 + r;
          *reinterpret_cast<unsigned short*>(
              A + ((row * 768 + 256 + col * 2) ^ ((row & 7) << 4))) =
              f2bf(acc[mt][q][r] + bias);
        }
    }
    __syncthreads();
    f32x4 aD[2][4], aSv[2][4];
#pragma unroll
    for (int mt = 0; mt < 2; ++mt)
#pragma unroll
      for (int q = 0; q < 4; ++q)
#pragma unroll
        for (int r = 0; r < 4; ++r) { aD[mt][q][r] = 0.f; aSv[mt][q][r] = 0.f; }
    const int r0p = lr * 768 + lg * 16, r1p = (16 + lr) * 768 + lg * 16;
#pragma unroll
    for (int kt = 0; kt < 8; ++kt) {
      const short8v a0 = *reinterpret_cast<const short8v*>(A + ((r0p + kt * 64) ^ sw));
      const short8v a1 = *reinterpret_cast<const short8v*>(A + ((r1p + kt * 64) ^ sw));
#pragma unroll
      for (int q = 0; q < 4; ++q) {
        const size_t bi = (((size_t)(kt * 16 + 4 * w + q) * 64 + l) << 3);
        const short8v bD = *reinterpret_cast<const short8v*>(wpd + bi);
        const short8v bSv = *reinterpret_cast<const short8v*>(wps + bi);
        aD[0][q] = __builtin_amdgcn_mfma_f32_16x16x32_bf16(a0, bD, aD[0][q], 0, 0, 0);
        aD[1][q] = __builtin_amdgcn_mfma_f32_16x16x32_bf16(a1, bD, aD[1][q], 0, 0, 0);
        aSv[0][q] = __builtin_amdgcn_mfma_f32_16x16x32_bf16(a0, bSv, aSv[0][q], 0, 0, 0);
        aSv[1][q] = __builtin_amdgcn_mfma_f32_16x16x32_bf16(a1, bSv, aSv[1][q], 0, 0, 0);
      }
    }
#pragma unroll
    for (int q = 0; q < 4; ++q) {
      const int col = (4 * w + q) * 16 + lr;
#pragma unroll
      for (int mt = 0; mt < 2; ++mt)
#pragma unroll
        for (int r = 0; r < 4; ++r) {
          const int row = mt * 16 + lg * 4 + r;
          PDo[(size_t)(n0 + row) * HH + col] = f2bf(aD[mt][q][r]);
          PSo[(size_t)(n0 + row) * HH + col] = f2bf(aSv[mt][q][r]);
        }
    }
  }

  if constexpr (HEADS) {
    __syncthreads();   // all MFMA reads of A done
    // A layout: [0,8192) nf tile bf16 ([32][128], stride 256B, swizzled);
    // [8192,16384) hid bf16; [16384,17408) part f32; [17408,21760) cw2 bf16.
    unsigned short* cw2b = reinterpret_cast<unsigned short*>(A + 17408);
    for (int j = t; j < DF * TT; j += 256) cw2b[j] = f2bf(cw2[j]);
#pragma unroll
    for (int q = 0; q < 2; ++q) {
      const int col = (2 * w + q) * 16 + lr;
      const float bias = b[col];
#pragma unroll
      for (int mt = 0; mt < 2; ++mt)
#pragma unroll
        for (int r = 0; r < 4; ++r) {
          const int row = mt * 16 + lg * 4 + r;
          *reinterpret_cast<unsigned short*>(
              A + ((row * 256 + col * 2) ^ ((row & 7) << 4))) =
              f2bf(acc[mt][q][r] + bias);
        }
    }
    __syncthreads();

    // ===== head 1: scalar (nc) =====
    f32x4 ah[2][2];
#pragma unroll
    for (int mt = 0; mt < 2; ++mt)
#pragma unroll
      for (int q = 0; q < 2; ++q)
#pragma unroll
        for (int r = 0; r < 4; ++r) ah[mt][q][r] = 0.f;
#pragma unroll
    for (int kt = 0; kt < 4; ++kt) {
      const short8v a0 = *reinterpret_cast<const short8v*>(
          A + ((row0 * 256 + kt * 64 + lg * 16) ^ sw));
      const short8v a1 = *reinterpret_cast<const short8v*>(
          A + ((row1 * 256 + kt * 64 + lg * 16) ^ sw));
#pragma unroll
      for (int q = 0; q < 2; ++q) {
        const short8v bq = *reinterpret_cast<const short8v*>(
            wpn + (((size_t)(kt * 8 + 2 * w + q) * 64 + l) << 3));
        ah[0][q] = __builtin_amdgcn_mfma_f32_16x16x32_bf16(a0, bq, ah[0][q], 0, 0, 0);
        ah[1][q] = __builtin_amdgcn_mfma_f32_16x16x32_bf16(a1, bq, ah[1][q], 0, 0, 0);
      }
    }
    unsigned short* hid = reinterpret_cast<unsigned short*>(A + 8192);
#pragma unroll
    for (int q = 0; q < 2; ++q) {
      const int col = (2 * w + q) * 16 + lr;
      const float bias = nb1[col];
#pragma unroll
      for (int mt = 0; mt < 2; ++mt)
#pragma unroll
        for (int r = 0; r < 4; ++r) {
          const int row = mt * 16 + lg * 4 + r;
          hid[row * 128 + col] = f2bf(fmaxf(ah[mt][q][r] + bias, 0.f));
        }
    }
    __syncthreads();
    float* part = reinterpret_cast<float*>(A + 16384);
    {
      const int rr = t >> 3, kc = t & 7;
      float s = 0.f;
#pragma unroll
      for (int u = 0; u < 16; ++u)
        s = fmaf(bf2f(hid[rr * 128 + kc * 16 + u]), nw2[kc * 16 + u], s);
      part[rr * 8 + kc] = s;
    }
    __syncthreads();
    if (t < 32) {
      float s = nb2[0];
#pragma unroll
      for (int k = 0; k < 8; ++k) s += part[t * 8 + k];
      out_pn[n0 + t] = s;
    }
    __syncthreads();   // before hid overwrite

    // ===== head 2: class (cc) =====
    f32x4 ac2[2][2];
#pragma unroll
    for (int mt = 0; mt < 2; ++mt)
#pragma unroll
      for (int q = 0; q < 2; ++q)
#pragma unroll
        for (int r = 0; r < 4; ++r) ac2[mt][q][r] = 0.f;
#pragma unroll
    for (int kt = 0; kt < 4; ++kt) {
      const short8v a0 = *reinterpret_cast<const short8v*>(
          A + ((row0 * 256 + kt * 64 + lg * 16) ^ sw));
      const short8v a1 = *reinterpret_cast<const short8v*>(
          A + ((row1 * 256 + kt * 64 + lg * 16) ^ sw));
#pragma unroll
      for (int q = 0; q < 2; ++q) {
        const short8v bq = *reinterpret_cast<const short8v*>(
            wpc + (((size_t)(kt * 8 + 2 * w + q) * 64 + l) << 3));
        ac2[0][q] = __builtin_amdgcn_mfma_f32_16x16x32_bf16(a0, bq, ac2[0][q], 0, 0, 0);
        ac2[1][q] = __builtin_amdgcn_mfma_f32_16x16x32_bf16(a1, bq, ac2[1][q], 0, 0, 0);
      }
    }
#pragma unroll
    for (int q = 0; q < 2; ++q) {
      const int col = (2 * w + q) * 16 + lr;
      const float bias = cb1[col];
#pragma unroll
      for (int mt = 0; mt < 2; ++mt)
#pragma unroll
        for (int r = 0; r < 4; ++r) {
          const int row = mt * 16 + lg * 4 + r;
          hid[row * 128 + col] = f2bf(fmaxf(ac2[mt][q][r] + bias, 0.f));
        }
    }
    __syncthreads();
    for (int o = t; o < 32 * TT; o += 256) {
      const int rr = o / TT, c = o - TT * rr;
      float s = cb2[c];
      for (int k = 0; k < DF; ++k)
        s = fmaf(bf2f(hid[rr * 128 + k]), bf2f(cw2b[k * TT + c]), s);
      out_pc[(size_t)(n0 + rr) * TT + c] = s;
    }
  }
}

// ---------------------------------------------------------------------------
extern "C" void kernel_launch(void* const* d_in, const int* in_sizes, int n_in,
                              void* d_out, int out_size, void* d_ws,
                              size_t ws_size, hipStream_t stream) {
  (void)in_sizes; (void)n_in; (void)out_size; (void)ws_size;
  const float* x         = (const float*)d_in[0];
  const float* edge_attr = (const float*)d_in[1];
  const int*   edge_idx  = (const int*)d_in[2];
  const int*   node_ty   = (const int*)d_in[3];
  const float* ne_w1 = (const float*)d_in[4];
  const float* ne_b1 = (const float*)d_in[5];
  const float* ne_w2 = (const float*)d_in[6];
  const float* ne_b2 = (const float*)d_in[7];
  const float* ee_w1 = (const float*)d_in[8];
  const float* ee_b1 = (const float*)d_in[9];
  const float* ee_w2 = (const float*)d_in[10];
  const float* ee_b2 = (const float*)d_in[11];
  const float* me_w1 = (const float*)d_in[12];
  const float* me_b1 = (const float*)d_in[13];
  const float* me_w2 = (const float*)d_in[14];
  const float* me_b2 = (const float*)d_in[15];
  const float* mn_w1 = (const float*)d_in[16];
  const float* mn_b1 = (const float*)d_in[17];
  const float* ec_w1 = (const float*)d_in[18];
  const float* ec_b1 = (const float*)d_in[19];
  const float* ec_w2 = (const float*)d_in[20];
  const float* ec_b2 = (const float*)d_in[21];
  const float* nc_w1 = (const float*)d_in[22];
  const float* nc_b1 = (const float*)d_in[23];
  const float* nc_w2 = (const float*)d_in[24];
  const float* nc_b2 = (const float*)d_in[25];
  const float* cc_w1 = (const float*)d_in[26];
  const float* cc_b1 = (const float*)d_in[27];
  const float* cc_w2 = (const float*)d_in[28];
  const float* cc_b2 = (const float*)d_in[29];

  const int* srcv = edge_idx;
  const int* dstv = edge_idx + N_EDGES;

  // ---- workspace layout ----
  unsigned short* nf0b = (unsigned short*)d_ws;
  unsigned short* nf1b = nf0b + (size_t)N_NODES * DF;
  unsigned short* ef0p = nf1b + (size_t)N_NODES * DF;      // PERMUTED ef0
  unsigned short* ef1p = ef0p + (size_t)N_EDGES * DF;      // PERMUTED ef
  unsigned short* wmpD = ef1p + (size_t)N_EDGES * DF;      // W1 rows 0:256
  unsigned short* wmpS = wmpD + 256 * 256;                 // W1 rows 256:512
  unsigned short* wmeE = wmpS + 256 * 256;                 // W1 rows 512:768
  unsigned short* wme2 = wmeE + 256 * 256;                 // 256x128
  unsigned short* wmn  = wme2 + 256 * 128;                 // 384x128
  unsigned short* wne1 = wmn + 384 * 128;                  // 17 x 256x128
  unsigned short* wne2 = wne1 + (size_t)TT * 256 * 128;    // 17 x 128x128
  unsigned short* wee1 = wne2 + (size_t)TT * 128 * 128;    // 64x128
  unsigned short* wee2 = wee1 + 64 * 128;                  // 128x128
  unsigned short* wec  = wee2 + 128 * 128;
  unsigned short* wnc  = wec + 128 * 128;
  unsigned short* wcc  = wnc + 128 * 128;
  unsigned short* PD   = wcc + 128 * 128;                  // [N][256] bf16
  unsigned short* PS   = PD + (size_t)N_NODES * HH;        // [N][256] bf16
  int* cnt    = (int*)(PS + (size_t)N_NODES * HH);
  int* woff   = cnt + 32;
  int* bucket = woff + 32;                                 // NE_PAD_SLOTS ints
  int* deg    = bucket + NE_PAD_SLOTS;                     // N
  int* rs     = deg + N_NODES;                             // N + 1
  int* wo     = rs + N_NODES + 1;                          // N
  int* elist  = wo + N_NODES;                              // E
  int* ipos   = elist + N_EDGES;                           // E
  int* srcp   = ipos + N_EDGES;                            // E
  int* dstp   = srcp + N_EDGES;                            // E

  // ---- output layout ----
  float* out_pe = (float*)d_out;
  float* out_pn = out_pe + N_EDGES;
  float* out_pc = out_pn + N_NODES;
  float* out_nf = out_pc + (size_t)N_NODES * TT;
  float* out_ef = out_nf + (size_t)N_NODES * DF;

  // ---- single-dispatch weight packing ----
  PackPtrs P;
  P.s0 = me_w1;            P.d0 = wmpD;
  P.s1 = me_w1 + 256*256;  P.d1 = wmpS;
  P.s2 = me_w1 + 512*256;  P.d2 = wmeE;
  P.s3 = me_w2;            P.d3 = wme2;
  P.s4 = mn_w1;            P.d4 = wmn;
  P.s5 = ne_w1;            P.d5 = wne1;
  P.s6 = ne_w2;            P.d6 = wne2;
  P.s7 = ee_w1;            P.d7 = wee1;
  P.s8 = ee_w2;            P.d8 = wee2;
  P.s9 = ec_w1;            P.d9 = wec;
  P.s10 = nc_w1;           P.d10 = wnc;
  P.s11 = cc_w1;           P.d11 = wcc;
  k_pack_all<<<580, 256, 0, stream>>>(P);

  // ---- setup (bucketing + CSR by dst, merged) ----
  hipMemsetAsync(cnt, 0, 32 * sizeof(int), stream);
  hipMemsetAsync(deg, 0, N_NODES * sizeof(int), stream);
  hipMemsetAsync(bucket, 0xFF, NE_PAD_SLOTS * sizeof(int), stream);
  k_count_deg<<<(N_EDGES + 255) / 256, 256, 0, stream>>>(node_ty, dstv, cnt, deg);
  k_prefix_scan<<<1, 1024, 0, stream>>>(cnt, woff, deg, rs, wo);
  k_scatter_elist<<<(N_EDGES + 255) / 256, 256, 0, stream>>>(
      node_ty, srcv, dstv, woff, wo, bucket, elist, ipos, srcp, dstp);

  // ---- fused embeddings (+ step-1 PD/PS partials in node blocks) ----
  k_embed_fused<<<NB_NODE + N_EDGES / 32, 256, 0, stream>>>(
      x, bucket, node_ty, wne1, ne_b1, wne2, ne_b2, nf0b, wmpD, wmpS, PD, PS,
      edge_attr, ipos, wee1, ee_b1, wee2, ee_b2, ef0p);

  // ---- mp step 1 (nf = nf0, ef = ef0) ----
  k_edge_mlp_mfma<false, false><<<N_EDGES / 32, 256, 0, stream>>>(
      ef0p, ef0p, ef1p, nullptr, srcp, dstp, elist, wmeE, me_b1, wme2, me_b2,
      PD, PS, nullptr, nullptr, nullptr, nullptr, nullptr);
  k_node_update_mfma<false, true, false><<<N_NODES / 32, 256, 0, stream>>>(
      nf0b, nf0b, ef1p, rs, (void*)nf1b, wmn, mn_b1, wmpD, wmpS, PD, PS,
      nullptr, nullptr, nullptr, nullptr, nullptr, nullptr, nullptr, nullptr,
      nullptr, nullptr);
  // ---- mp step 2 (fused edge head -> out_pe) ----
  k_edge_mlp_mfma<false, true><<<N_EDGES / 32, 256, 0, stream>>>(
      ef0p, ef1p, ef1p, nullptr, srcp, dstp, elist, wmeE, me_b1, wme2, me_b2,
      PD, PS, wec, ec_b1, ec_w2, ec_b2, out_pe);
  k_node_update_mfma<false, true, false><<<N_NODES / 32, 256, 0, stream>>>(
      nf0b, nf1b, ef1p, rs, (void*)nf1b, wmn, mn_b1, wmpD, wmpS, PD, PS,
      nullptr, nullptr, nullptr, nullptr, nullptr, nullptr, nullptr, nullptr,
      nullptr, nullptr);
  // ---- mp step 3 (ef out + fused node heads) ----
  k_edge_mlp_mfma<true, false><<<N_EDGES / 32, 256, 0, stream>>>(
      ef0p, ef1p, ef1p, out_ef, srcp, dstp, elist, wmeE, me_b1, wme2, me_b2,
      PD, PS, nullptr, nullptr, nullptr, nullptr, nullptr);
  k_node_update_mfma<true, false, true><<<N_NODES / 32, 256, 0, stream>>>(
      nf0b, nf1b, ef1p, rs, (void*)out_nf, wmn, mn_b1, wmpD, wmpS, PD, PS,
      wnc, nc_b1, nc_w2, nc_b2, wcc, cc_b1, cc_w2, cc_b2, out_pn, out_pc);
}

// Round 13
// 531.443 us; speedup vs baseline: 1.0574x; 1.0574x over previous
//
#include <hip/hip_runtime.h>
#include <hip/hip_bf16.h>

#define N_NODES 20000
#define N_EDGES 160000
#define DIN_NODE 256
#define DIN_EDGE 64
#define DF 128      // feature dim
#define HH 256      // edge-MLP hidden dim
#define TT 17       // node types
#define NE_PAD_SLOTS 20544   // 642 blocks * 32 (type-padded bucket list)
#define NB_NODE (NE_PAD_SLOTS / 32)   // 642 node-embed blocks

typedef __attribute__((ext_vector_type(8))) short short8v;   // 8 bf16
typedef __attribute__((ext_vector_type(4))) float f32x4;     // MFMA C/D frag

// fp32 -> bf16 round-to-nearest-even
__device__ __forceinline__ unsigned short f2bf(float f) {
  unsigned int u = __builtin_bit_cast(unsigned int, f);
  u += 0x7FFFu + ((u >> 16) & 1u);
  return (unsigned short)(u >> 16);
}

__device__ __forceinline__ float bf2f(unsigned short u) {
  return __builtin_bit_cast(float, (unsigned int)u << 16);
}

__device__ __forceinline__ short8v pack8(float4 a, float4 b) {
  short8v o;
  o[0] = (short)f2bf(a.x); o[1] = (short)f2bf(a.y);
  o[2] = (short)f2bf(a.z); o[3] = (short)f2bf(a.w);
  o[4] = (short)f2bf(b.x); o[5] = (short)f2bf(b.y);
  o[6] = (short)f2bf(b.z); o[7] = (short)f2bf(b.w);
  return o;
}

// ---------------------------------------------------------------------------
// Pack ALL weights in one dispatch.  2320 tiles total, 4 tiles/block.
// ---------------------------------------------------------------------------
struct PackPtrs {
  const float *s0, *s1, *s2, *s3, *s4, *s5, *s6, *s7, *s8, *s9, *s10, *s11;
  unsigned short *d0, *d1, *d2, *d3, *d4, *d5, *d6, *d7, *d8, *d9, *d10, *d11;
};

__global__ __launch_bounds__(256) void k_pack_all(PackPtrs P) {
  const int g = blockIdx.x * 4 + (threadIdx.x >> 6);
  const int l = threadIdx.x & 63;
  if (g >= 2320) return;
  const float* w; unsigned short* out; int K, N, tile;
  if (g < 128)       { w = P.s0;  out = P.d0;  K = 256; N = 256; tile = g; }
  else if (g < 256)  { w = P.s1;  out = P.d1;  K = 256; N = 256; tile = g - 128; }
  else if (g < 384)  { w = P.s2;  out = P.d2;  K = 256; N = 256; tile = g - 256; }
  else if (g < 448)  { w = P.s3;  out = P.d3;  K = 256; N = 128; tile = g - 384; }
  else if (g < 544)  { w = P.s4;  out = P.d4;  K = 384; N = 128; tile = g - 448; }
  else if (g < 1632) { w = P.s5;  out = P.d5;  K = 256; N = 128; tile = g - 544; }
  else if (g < 2176) { w = P.s6;  out = P.d6;  K = 128; N = 128; tile = g - 1632; }
  else if (g < 2192) { w = P.s7;  out = P.d7;  K = 64;  N = 128; tile = g - 2176; }
  else if (g < 2224) { w = P.s8;  out = P.d8;  K = 128; N = 128; tile = g - 2192; }
  else if (g < 2256) { w = P.s9;  out = P.d9;  K = 128; N = 128; tile = g - 2224; }
  else if (g < 2288) { w = P.s10; out = P.d10; K = 128; N = 128; tile = g - 2256; }
  else               { w = P.s11; out = P.d11; K = 128; N = 128; tile = g - 2288; }
  const int ntTiles = N >> 4;
  const int tilesPer = (K >> 5) * ntTiles;
  const int bt = tile / tilesPer;
  const int rr = tile - bt * tilesPer;
  const int kt = rr / ntTiles, nt = rr - kt * ntTiles;
  const float* wb = w + (size_t)bt * K * N;
  const int col = (nt << 4) + (l & 15);
  const int k0 = (kt << 5) + ((l >> 4) << 3);
  unsigned short* o = out + (((size_t)tile << 6) + l) * 8;
#pragma unroll
  for (int j = 0; j < 8; ++j) o[j] = f2bf(wb[(size_t)(k0 + j) * N + col]);
}

// ---------------------------------------------------------------------------
// Setup: merged count (node types + dst degree), merged scans, merged scatter.
// ---------------------------------------------------------------------------
__global__ void k_count_deg(const int* __restrict__ types,
                            const int* __restrict__ dstv,
                            int* __restrict__ cnt, int* __restrict__ deg) {
  const int i = blockIdx.x * 256 + threadIdx.x;
  if (i < N_NODES) atomicAdd(&cnt[types[i]], 1);
  if (i < N_EDGES) atomicAdd(&deg[dstv[i]], 1);
}

__global__ __launch_bounds__(1024) void k_prefix_scan(
    const int* __restrict__ cnt, int* __restrict__ woff,
    const int* __restrict__ deg, int* __restrict__ rs, int* __restrict__ wo) {
  __shared__ int partial[1024];
  const int t = threadIdx.x;
  if (t == 0) {
    int cur = 0;
    for (int ty = 0; ty < TT; ++ty) {
      woff[ty] = cur;
      cur += (cnt[ty] + 31) & ~31;
    }
  }
  const int base = t * 20;
  int s = 0;
  for (int j = 0; j < 20; ++j) {
    const int n = base + j;
    if (n < N_NODES) s += deg[n];
  }
  partial[t] = s;
  __syncthreads();
  for (int off = 1; off < 1024; off <<= 1) {
    const int v = (t >= off) ? partial[t - off] : 0;
    __syncthreads();
    partial[t] += v;
    __syncthreads();
  }
  int run = (t > 0) ? partial[t - 1] : 0;
  for (int j = 0; j < 20; ++j) {
    const int n = base + j;
    if (n < N_NODES) {
      rs[n] = run; wo[n] = run;
      run += deg[n];
    }
  }
  if (t == 1023) rs[N_NODES] = run;
}

__global__ void k_scatter_elist(const int* __restrict__ types,
                                const int* __restrict__ srcv,
                                const int* __restrict__ dstv,
                                int* __restrict__ woff, int* __restrict__ wo,
                                int* __restrict__ bucket,
                                int* __restrict__ elist, int* __restrict__ ipos,
                                int* __restrict__ srcp, int* __restrict__ dstp) {
  const int i = blockIdx.x * 256 + threadIdx.x;
  if (i < N_NODES) {
    const int pos = atomicAdd(&woff[types[i]], 1);
    bucket[pos] = i;
  }
  if (i < N_EDGES) {
    const int pos = atomicAdd(&wo[dstv[i]], 1);
    elist[pos] = i;
    ipos[i] = pos;
    srcp[pos] = srcv[i];
    dstp[pos] = dstv[i];
  }
}

// ---------------------------------------------------------------------------
// Fused embedding dispatch (unchanged, passing).
// ---------------------------------------------------------------------------
__global__ __launch_bounds__(256) void k_embed_fused(
    const float* __restrict__ x, const int* __restrict__ bucket,
    const int* __restrict__ types,
    const unsigned short* __restrict__ wp1, const float* __restrict__ b1,
    const unsigned short* __restrict__ wp2, const float* __restrict__ b2,
    unsigned short* __restrict__ nf0b,
    const unsigned short* __restrict__ wpd, const unsigned short* __restrict__ wps,
    unsigned short* __restrict__ PDo, unsigned short* __restrict__ PSo,
    const float* __restrict__ ea, const int* __restrict__ ipos,
    const unsigned short* __restrict__ ewp1, const float* __restrict__ eb1,
    const unsigned short* __restrict__ ewp2, const float* __restrict__ eb2,
    unsigned short* __restrict__ ef0p) {
  __shared__ __align__(16) unsigned char A[32 * 512];   // 16 KB
  __shared__ __align__(16) unsigned char Hb[32 * 256];  // 8 KB
  __shared__ int sidx[32];
  const int t = threadIdx.x;
  const int w = t >> 6, l = t & 63, lr = l & 15, lg = l >> 4;
  const int sw = (lr & 7) << 4;
  const int row0 = lr, row1 = 16 + lr;

  if (blockIdx.x < NB_NODE) {
    // ================= node path =================
    const int r0 = blockIdx.x * 32;
    if (t < 32) sidx[t] = bucket[r0 + t];
    __syncthreads();
    if (sidx[0] < 0) return;
    const int ty = types[sidx[0]];

#pragma unroll
    for (int j = 0; j < 4; ++j) {
      const int q = j * 256 + t;
      const int i = q >> 5, c = q & 31;
      const int nd = sidx[i];
      short8v o;
      if (nd >= 0) {
        const float* xr = x + (size_t)nd * DIN_NODE + c * 8;
        o = pack8(*reinterpret_cast<const float4*>(xr),
                  *reinterpret_cast<const float4*>(xr + 4));
      } else {
#pragma unroll
        for (int k = 0; k < 8; ++k) o[k] = 0;
      }
      *reinterpret_cast<short8v*>(A + ((i * 512 + c * 16) ^ ((i & 7) << 4))) = o;
    }
    __syncthreads();

    f32x4 acc[2][2];
#pragma unroll
    for (int mt = 0; mt < 2; ++mt)
#pragma unroll
      for (int q = 0; q < 2; ++q)
#pragma unroll
        for (int r = 0; r < 4; ++r) acc[mt][q][r] = 0.f;
#pragma unroll
    for (int kt = 0; kt < 8; ++kt) {
      const short8v a0 = *reinterpret_cast<const short8v*>(
          A + ((row0 * 512 + kt * 64 + lg * 16) ^ sw));
      const short8v a1 = *reinterpret_cast<const short8v*>(
          A + ((row1 * 512 + kt * 64 + lg * 16) ^ sw));
#pragma unroll
      for (int q = 0; q < 2; ++q) {
        const short8v bq = *reinterpret_cast<const short8v*>(
            wp1 + (((size_t)(ty * 64 + kt * 8 + 2 * w + q) * 64 + l) << 3));
        acc[0][q] = __builtin_amdgcn_mfma_f32_16x16x32_bf16(a0, bq, acc[0][q], 0, 0, 0);
        acc[1][q] = __builtin_amdgcn_mfma_f32_16x16x32_bf16(a1, bq, acc[1][q], 0, 0, 0);
      }
    }
#pragma unroll
    for (int q = 0; q < 2; ++q) {
      const int col = (2 * w + q) * 16 + lr;
      const float bias = b1[ty * DF + col];
#pragma unroll
      for (int mt = 0; mt < 2; ++mt)
#pragma unroll
        for (int r = 0; r < 4; ++r) {
          const int row = mt * 16 + lg * 4 + r;
          *reinterpret_cast<unsigned short*>(
              Hb + ((row * 256 + col * 2) ^ ((row & 7) << 4))) =
              f2bf(fmaxf(acc[mt][q][r] + bias, 0.f));
        }
    }
    __syncthreads();

    f32x4 acc2[2][2];
#pragma unroll
    for (int mt = 0; mt < 2; ++mt)
#pragma unroll
      for (int q = 0; q < 2; ++q)
#pragma unroll
        for (int r = 0; r < 4; ++r) acc2[mt][q][r] = 0.f;
#pragma unroll
    for (int kt = 0; kt < 4; ++kt) {
      const short8v a0 = *reinterpret_cast<const short8v*>(
          Hb + ((row0 * 256 + kt * 64 + lg * 16) ^ sw));
      const short8v a1 = *reinterpret_cast<const short8v*>(
          Hb + ((row1 * 256 + kt * 64 + lg * 16) ^ sw));
#pragma unroll
      for (int q = 0; q < 2; ++q) {
        const short8v bq = *reinterpret_cast<const short8v*>(
            wp2 + (((size_t)(ty * 32 + kt * 8 + 2 * w + q) * 64 + l) << 3));
        acc2[0][q] = __builtin_amdgcn_mfma_f32_16x16x32_bf16(a0, bq, acc2[0][q], 0, 0, 0);
        acc2[1][q] = __builtin_amdgcn_mfma_f32_16x16x32_bf16(a1, bq, acc2[1][q], 0, 0, 0);
      }
    }
    // write nf0 to global AND into A as [nf0|nf0] for the fused partial
#pragma unroll
    for (int q = 0; q < 2; ++q) {
      const int col = (2 * w + q) * 16 + lr;
      const float bias = b2[ty * DF + col];
#pragma unroll
      for (int mt = 0; mt < 2; ++mt)
#pragma unroll
        for (int r = 0; r < 4; ++r) {
          const int row = mt * 16 + lg * 4 + r;
          const int nd = sidx[row];
          const unsigned short v = f2bf(acc2[mt][q][r] + bias);
          if (nd >= 0) nf0b[(size_t)nd * DF + col] = v;
          *reinterpret_cast<unsigned short*>(
              A + ((row * 512 + col * 2) ^ ((row & 7) << 4))) = v;
          *reinterpret_cast<unsigned short*>(
              A + ((row * 512 + (col + 128) * 2) ^ ((row & 7) << 4))) = v;
        }
    }
    __syncthreads();

    // fused step-1 partials: PD/PS = [nf0|nf0] @ wpd/wps (K=256)
    f32x4 aD[2][4], aS[2][4];
#pragma unroll
    for (int mt = 0; mt < 2; ++mt)
#pragma unroll
      for (int q = 0; q < 4; ++q)
#pragma unroll
        for (int r = 0; r < 4; ++r) { aD[mt][q][r] = 0.f; aS[mt][q][r] = 0.f; }
    const int r0o = lr * 512 + lg * 16, r1o = (16 + lr) * 512 + lg * 16;
#pragma unroll
    for (int kt = 0; kt < 8; ++kt) {
      const short8v a0 = *reinterpret_cast<const short8v*>(A + ((r0o + kt * 64) ^ sw));
      const short8v a1 = *reinterpret_cast<const short8v*>(A + ((r1o + kt * 64) ^ sw));
#pragma unroll
      for (int q = 0; q < 4; ++q) {
        const size_t bi = (((size_t)(kt * 16 + 4 * w + q) * 64 + l) << 3);
        const short8v bD = *reinterpret_cast<const short8v*>(wpd + bi);
        const short8v bS = *reinterpret_cast<const short8v*>(wps + bi);
        aD[0][q] = __builtin_amdgcn_mfma_f32_16x16x32_bf16(a0, bD, aD[0][q], 0, 0, 0);
        aD[1][q] = __builtin_amdgcn_mfma_f32_16x16x32_bf16(a1, bD, aD[1][q], 0, 0, 0);
        aS[0][q] = __builtin_amdgcn_mfma_f32_16x16x32_bf16(a0, bS, aS[0][q], 0, 0, 0);
        aS[1][q] = __builtin_amdgcn_mfma_f32_16x16x32_bf16(a1, bS, aS[1][q], 0, 0, 0);
      }
    }
#pragma unroll
    for (int q = 0; q < 4; ++q) {
      const int col = (4 * w + q) * 16 + lr;
#pragma unroll
      for (int mt = 0; mt < 2; ++mt)
#pragma unroll
        for (int r = 0; r < 4; ++r) {
          const int row = mt * 16 + lg * 4 + r;
          const int nd = sidx[row];
          if (nd >= 0) {
            PDo[(size_t)nd * HH + col] = f2bf(aD[mt][q][r]);
            PSo[(size_t)nd * HH + col] = f2bf(aS[mt][q][r]);
          }
        }
    }
  } else {
    // ================= edge path =================
    const int e0 = (blockIdx.x - NB_NODE) * 32;
    if (t < 32) sidx[t] = ipos[e0 + t];
    {
      const int i = t >> 3, c = t & 7;
      const float* xr = ea + (size_t)(e0 + i) * DIN_EDGE + c * 8;
      const short8v o = pack8(*reinterpret_cast<const float4*>(xr),
                              *reinterpret_cast<const float4*>(xr + 4));
      *reinterpret_cast<short8v*>(A + ((i * 128 + c * 16) ^ ((i & 7) << 4))) = o;
    }
    __syncthreads();

    f32x4 acc[2][2];
#pragma unroll
    for (int mt = 0; mt < 2; ++mt)
#pragma unroll
      for (int q = 0; q < 2; ++q)
#pragma unroll
        for (int r = 0; r < 4; ++r) acc[mt][q][r] = 0.f;
#pragma unroll
    for (int kt = 0; kt < 2; ++kt) {
      const short8v a0 = *reinterpret_cast<const short8v*>(
          A + ((row0 * 128 + kt * 64 + lg * 16) ^ sw));
      const short8v a1 = *reinterpret_cast<const short8v*>(
          A + ((row1 * 128 + kt * 64 + lg * 16) ^ sw));
#pragma unroll
      for (int q = 0; q < 2; ++q) {
        const short8v bq = *reinterpret_cast<const short8v*>(
            ewp1 + (((size_t)(kt * 8 + 2 * w + q) * 64 + l) << 3));
        acc[0][q] = __builtin_amdgcn_mfma_f32_16x16x32_bf16(a0, bq, acc[0][q], 0, 0, 0);
        acc[1][q] = __builtin_amdgcn_mfma_f32_16x16x32_bf16(a1, bq, acc[1][q], 0, 0, 0);
      }
    }
#pragma unroll
    for (int q = 0; q < 2; ++q) {
      const int col = (2 * w + q) * 16 + lr;
      const float bias = eb1[col];
#pragma unroll
      for (int mt = 0; mt < 2; ++mt)
#pragma unroll
        for (int r = 0; r < 4; ++r) {
          const int row = mt * 16 + lg * 4 + r;
          *reinterpret_cast<unsigned short*>(
              Hb + ((row * 256 + col * 2) ^ ((row & 7) << 4))) =
              f2bf(fmaxf(acc[mt][q][r] + bias, 0.f));
        }
    }
    __syncthreads();

    f32x4 acc2[2][2];
#pragma unroll
    for (int mt = 0; mt < 2; ++mt)
#pragma unroll
      for (int q = 0; q < 2; ++q)
#pragma unroll
        for (int r = 0; r < 4; ++r) acc2[mt][q][r] = 0.f;
#pragma unroll
    for (int kt = 0; kt < 4; ++kt) {
      const short8v a0 = *reinterpret_cast<const short8v*>(
          Hb + ((row0 * 256 + kt * 64 + lg * 16) ^ sw));
      const short8v a1 = *reinterpret_cast<const short8v*>(
          Hb + ((row1 * 256 + kt * 64 + lg * 16) ^ sw));
#pragma unroll
      for (int q = 0; q < 2; ++q) {
        const short8v bq = *reinterpret_cast<const short8v*>(
            ewp2 + (((size_t)(kt * 8 + 2 * w + q) * 64 + l) << 3));
        acc2[0][q] = __builtin_amdgcn_mfma_f32_16x16x32_bf16(a0, bq, acc2[0][q], 0, 0, 0);
        acc2[1][q] = __builtin_amdgcn_mfma_f32_16x16x32_bf16(a1, bq, acc2[1][q], 0, 0, 0);
      }
    }
#pragma unroll
    for (int q = 0; q < 2; ++q) {
      const int col = (2 * w + q) * 16 + lr;
      const float bias = eb2[col];
#pragma unroll
      for (int mt = 0; mt < 2; ++mt)
#pragma unroll
        for (int r = 0; r < 4; ++r) {
          const int row = mt * 16 + lg * 4 + r;
          ef0p[(size_t)sidx[row] * DF + col] = f2bf(acc2[mt][q][r] + bias);
        }
    }
  }
}

// ---------------------------------------------------------------------------
// Edge MLP (R11 version, verbatim): overlapped staging, one barrier,
// __launch_bounds__(256,4), se[] in LDS, hpart unconditional.
// ---------------------------------------------------------------------------
template <bool OUTF, bool HEAD>
__global__ __launch_bounds__(256, 4) void k_edge_mlp_mfma(
    const unsigned short* __restrict__ ef0, const unsigned short* __restrict__ ef_in,
    unsigned short* __restrict__ ef_out, float* __restrict__ ef_outf,
    const int* __restrict__ srcp, const int* __restrict__ dstp,
    const int* __restrict__ elist,
    const unsigned short* __restrict__ wpe, const float* __restrict__ b1,
    const unsigned short* __restrict__ wp2, const float* __restrict__ b2,
    const unsigned short* __restrict__ PDi, const unsigned short* __restrict__ PSi,
    const unsigned short* __restrict__ wech, const float* __restrict__ hb1,
    const float* __restrict__ hw2, const float* __restrict__ hb2,
    float* __restrict__ out_pe) {
  __shared__ __align__(16) unsigned char A_lds[32 * 512];  // [ef0|ef] 16 KB
  __shared__ __align__(16) unsigned char P_lds[32 * 512];  // Pre / hidden 16 KB
  __shared__ int se[32];
  __shared__ float hpart[32][8];
  const int t = threadIdx.x;
  const int e0 = blockIdx.x * 32;
  if ((OUTF || HEAD) && t < 32) se[t] = elist[e0 + t];

  // ---- issue A loads and Pre loads together (one overlapped round trip) ----
  short8v av[4], pdv[4], psv[4];
#pragma unroll
  for (int j = 0; j < 4; ++j) {
    const int q = j * 256 + t;
    const int i = q >> 5, c = q & 31;
    const unsigned short* bp = (c < 16)
        ? ef0 + (size_t)(e0 + i) * DF + c * 8
        : ef_in + (size_t)(e0 + i) * DF + (c - 16) * 8;
    av[j] = *reinterpret_cast<const short8v*>(bp);
  }
#pragma unroll
  for (int j = 0; j < 4; ++j) {
    const int q = j * 256 + t;
    const int i = q >> 5, c = q & 31;
    const int dn = dstp[e0 + i];
    const int sn = srcp[e0 + i];
    pdv[j] = *reinterpret_cast<const short8v*>(PDi + (size_t)dn * HH + c * 8);
    psv[j] = *reinterpret_cast<const short8v*>(PSi + (size_t)sn * HH + c * 8);
  }
  // write both LDS buffers
#pragma unroll
  for (int j = 0; j < 4; ++j) {
    const int q = j * 256 + t;
    const int i = q >> 5, c = q & 31;
    const int off = (i * 512 + c * 16) ^ ((i & 7) << 4);
    *reinterpret_cast<short8v*>(A_lds + off) = av[j];
    short8v o;
#pragma unroll
    for (int k = 0; k < 8; ++k)
      o[k] = (short)f2bf(bf2f((unsigned short)pdv[j][k]) +
                         bf2f((unsigned short)psv[j][k]));
    *reinterpret_cast<short8v*>(P_lds + off) = o;
  }
  __syncthreads();

  const int w = t >> 6, l = t & 63, lr = l & 15, lg = l >> 4;
  const int swz = (lr & 7) << 4;

  // ---- layer 1: acc init from Pre, then [32x256]@[256x256] ----------------
  f32x4 acc[2][4];
#pragma unroll
  for (int mt = 0; mt < 2; ++mt)
#pragma unroll
    for (int q = 0; q < 4; ++q) {
      const int col = (4 * w + q) * 16 + lr;
#pragma unroll
      for (int r = 0; r < 4; ++r) {
        const int row = mt * 16 + lg * 4 + r;
        const unsigned short u = *reinterpret_cast<const unsigned short*>(
            P_lds + ((row * 512 + col * 2) ^ ((row & 7) << 4)));
        acc[mt][q][r] = bf2f(u);
      }
    }

  const int r0o = lr * 512 + lg * 16;
  const int r1o = (16 + lr) * 512 + lg * 16;
  const unsigned short* wb1 = wpe + (((size_t)(4 * w) * 64 + l) << 3);

  short8v aR[3][2], bR[3][4];
#pragma unroll
  for (int s = 0; s < 2; ++s) {
    aR[s][0] = *reinterpret_cast<const short8v*>(A_lds + ((r0o + s * 64) ^ swz));
    aR[s][1] = *reinterpret_cast<const short8v*>(A_lds + ((r1o + s * 64) ^ swz));
#pragma unroll
    for (int q = 0; q < 4; ++q)
      bR[s][q] = *reinterpret_cast<const short8v*>(wb1 + (size_t)s * 8192 + q * 512);
  }
#pragma unroll
  for (int kt = 0; kt < 8; ++kt) {
    const int cur = kt % 3, pf = (kt + 2) % 3;
    if (kt < 6) {
      aR[pf][0] = *reinterpret_cast<const short8v*>(
          A_lds + ((r0o + (kt + 2) * 64) ^ swz));
      aR[pf][1] = *reinterpret_cast<const short8v*>(
          A_lds + ((r1o + (kt + 2) * 64) ^ swz));
#pragma unroll
      for (int q = 0; q < 4; ++q)
        bR[pf][q] = *reinterpret_cast<const short8v*>(
            wb1 + (size_t)(kt + 2) * 8192 + q * 512);
    }
#pragma unroll
    for (int q = 0; q < 4; ++q) {
      acc[0][q] = __builtin_amdgcn_mfma_f32_16x16x32_bf16(aR[cur][0], bR[cur][q],
                                                          acc[0][q], 0, 0, 0);
      acc[1][q] = __builtin_amdgcn_mfma_f32_16x16x32_bf16(aR[cur][1], bR[cur][q],
                                                          acc[1][q], 0, 0, 0);
    }
  }
  __syncthreads();   // done reading A_lds and P_lds

  // hidden (bias+relu) -> bf16 [32][256], overwrites P_lds
#pragma unroll
  for (int q = 0; q < 4; ++q) {
    const int col = (4 * w + q) * 16 + lr;
    const float bias = b1[col];
#pragma unroll
    for (int mt = 0; mt < 2; ++mt)
#pragma unroll
      for (int r = 0; r < 4; ++r) {
        const int row = mt * 16 + lg * 4 + r;
        *reinterpret_cast<unsigned short*>(
            P_lds + ((row * 512 + col * 2) ^ ((row & 7) << 4))) =
            f2bf(fmaxf(acc[mt][q][r] + bias, 0.f));
      }
  }
  __syncthreads();

  // ---- layer 2: [32x256] @ [256x128] ---------------------------------------
  f32x4 acc2[2][2];
#pragma unroll
  for (int mt = 0; mt < 2; ++mt)
#pragma unroll
    for (int q = 0; q < 2; ++q)
#pragma unroll
      for (int r = 0; r < 4; ++r) acc2[mt][q][r] = 0.f;

  const int h0o = lr * 512 + lg * 16;
  const int h1o = (16 + lr) * 512 + lg * 16;
  const unsigned short* wb2 = wp2 + (((size_t)(2 * w) * 64 + l) << 3);

  short8v aS[3][2], bS[3][2];
#pragma unroll
  for (int s = 0; s < 2; ++s) {
    aS[s][0] = *reinterpret_cast<const short8v*>(P_lds + ((h0o + s * 64) ^ swz));
    aS[s][1] = *reinterpret_cast<const short8v*>(P_lds + ((h1o + s * 64) ^ swz));
#pragma unroll
    for (int q = 0; q < 2; ++q)
      bS[s][q] = *reinterpret_cast<const short8v*>(wb2 + (size_t)s * 4096 + q * 512);
  }
#pragma unroll
  for (int kt = 0; kt < 8; ++kt) {
    const int cur = kt % 3, pf = (kt + 2) % 3;
    if (kt < 6) {
      aS[pf][0] = *reinterpret_cast<const short8v*>(
          P_lds + ((h0o + (kt + 2) * 64) ^ swz));
      aS[pf][1] = *reinterpret_cast<const short8v*>(
          P_lds + ((h1o + (kt + 2) * 64) ^ swz));
#pragma unroll
      for (int q = 0; q < 2; ++q)
        bS[pf][q] = *reinterpret_cast<const short8v*>(
            wb2 + (size_t)(kt + 2) * 4096 + q * 512);
    }
#pragma unroll
    for (int q = 0; q < 2; ++q) {
      acc2[0][q] = __builtin_amdgcn_mfma_f32_16x16x32_bf16(aS[cur][0], bS[cur][q],
                                                           acc2[0][q], 0, 0, 0);
      acc2[1][q] = __builtin_amdgcn_mfma_f32_16x16x32_bf16(aS[cur][1], bS[cur][q],
                                                           acc2[1][q], 0, 0, 0);
    }
  }

  // ---- epilogue: bias, store e_new (permuted bf16; + fp32 scatter if OUTF) --
#pragma unroll
  for (int q = 0; q < 2; ++q) {
    const int n = (2 * w + q) * 16 + lr;
    const float bias = b2[n];
#pragma unroll
    for (int mt = 0; mt < 2; ++mt)
#pragma unroll
      for (int r = 0; r < 4; ++r) {
        const int m = mt * 16 + lg * 4 + r;
        const float v = acc2[mt][q][r] + bias;
        ef_out[(size_t)(e0 + m) * DF + n] = f2bf(v);
        if (OUTF)
          ef_outf[(size_t)se[m] * DF + n] = v;
      }
  }

  // ---- fused edge classifier head (step 2 only) ----------------------------
  if constexpr (HEAD) {
    __syncthreads();   // all layer-2 reads of P_lds done
#pragma unroll
    for (int q = 0; q < 2; ++q) {
      const int n = (2 * w + q) * 16 + lr;
      const float bias = b2[n];
#pragma unroll
      for (int mt = 0; mt < 2; ++mt)
#pragma unroll
        for (int r = 0; r < 4; ++r) {
          const int m = mt * 16 + lg * 4 + r;
          *reinterpret_cast<unsigned short*>(
              P_lds + ((m * 256 + n * 2) ^ ((m & 7) << 4))) =
              f2bf(acc2[mt][q][r] + bias);
        }
    }
    __syncthreads();
    f32x4 ah[2][2];
#pragma unroll
    for (int mt = 0; mt < 2; ++mt)
#pragma unroll
      for (int q = 0; q < 2; ++q)
#pragma unroll
        for (int r = 0; r < 4; ++r) ah[mt][q][r] = 0.f;
#pragma unroll
    for (int kt = 0; kt < 4; ++kt) {
      const short8v a0 = *reinterpret_cast<const short8v*>(
          P_lds + ((lr * 256 + kt * 64 + lg * 16) ^ swz));
      const short8v a1 = *reinterpret_cast<const short8v*>(
          P_lds + (((16 + lr) * 256 + kt * 64 + lg * 16) ^ swz));
#pragma unroll
      for (int q = 0; q < 2; ++q) {
        const short8v bq = *reinterpret_cast<const short8v*>(
            wech + (((size_t)(kt * 8 + 2 * w + q) * 64 + l) << 3));
        ah[0][q] = __builtin_amdgcn_mfma_f32_16x16x32_bf16(a0, bq, ah[0][q], 0, 0, 0);
        ah[1][q] = __builtin_amdgcn_mfma_f32_16x16x32_bf16(a1, bq, ah[1][q], 0, 0, 0);
      }
    }
#pragma unroll
    for (int q = 0; q < 2; ++q) {
      const int col = (2 * w + q) * 16 + lr;
      const float bias = hb1[col];
#pragma unroll
      for (int mt = 0; mt < 2; ++mt)
#pragma unroll
        for (int r = 0; r < 4; ++r) {
          const int row = mt * 16 + lg * 4 + r;
          *reinterpret_cast<unsigned short*>(A_lds + row * 256 + col * 2) =
              f2bf(fmaxf(ah[mt][q][r] + bias, 0.f));
        }
    }
    __syncthreads();
    {
      const int rr = t >> 3, kc = t & 7;
      float s = 0.f;
#pragma unroll
      for (int u = 0; u < 16; ++u)
        s = fmaf(bf2f(*reinterpret_cast<const unsigned short*>(
                     A_lds + rr * 256 + (kc * 16 + u) * 2)),
                 hw2[kc * 16 + u], s);
      hpart[rr][kc] = s;
    }
    __syncthreads();
    if (t < 32) {
      float s = hb2[0];
#pragma unroll
      for (int k = 0; k < 8; ++k) s += hpart[t][k];
      out_pe[se[t]] = s;
    }
  }
}

// ---------------------------------------------------------------------------
// Node update: CONTIGUOUS CSR gather + fused PART (steps 1-2) or fused node
// heads (HEADS, step 3).  (R12 version, kept — it was a win.)
// ---------------------------------------------------------------------------
template <bool OUTF, bool PART, bool HEADS>
__global__ __launch_bounds__(256) void k_node_update_mfma(
    const unsigned short* __restrict__ nf0, const unsigned short* __restrict__ nfb,
    const unsigned short* __restrict__ efp,
    const int* __restrict__ rs, void* __restrict__ outp,
    const unsigned short* __restrict__ wp, const float* __restrict__ b,
    const unsigned short* __restrict__ wpd, const unsigned short* __restrict__ wps,
    unsigned short* __restrict__ PDo, unsigned short* __restrict__ PSo,
    const unsigned short* __restrict__ wpn, const float* __restrict__ nb1,
    const float* __restrict__ nw2, const float* __restrict__ nb2,
    const unsigned short* __restrict__ wpc, const float* __restrict__ cb1,
    const float* __restrict__ cw2, const float* __restrict__ cb2,
    float* __restrict__ out_pn, float* __restrict__ out_pc) {
  __shared__ __align__(16) unsigned char A[32 * 768];   // 32 x 384 bf16, 24 KB
  const int t = threadIdx.x;
  const int n0 = blockIdx.x * 32;
#pragma unroll
  for (int j = 0; j < 4; ++j) {
    const int q = j * 256 + t;
    const int i = q >> 5, c = q & 31;
    const unsigned short* bp = (c < 16)
        ? nf0 + (size_t)(n0 + i) * DF + c * 8
        : nfb + (size_t)(n0 + i) * DF + (c - 16) * 8;
    *reinterpret_cast<short8v*>(A + ((i * 768 + c * 16) ^ ((i & 7) << 4))) =
        *reinterpret_cast<const short8v*>(bp);
  }
  // CSR aggregation into part 2: 8 threads/node, 16 dims each, CONTIGUOUS rows
  {
    const int i = t >> 3, sub = t & 7;
    const int n = n0 + i;
    const int kb = rs[n], ke = rs[n + 1];
    float av[16];
#pragma unroll
    for (int u = 0; u < 16; ++u) av[u] = 0.f;
    for (int k = kb; k < ke; ++k) {
      const unsigned short* er = efp + (size_t)k * DF + sub * 16;
      const short8v v0 = *reinterpret_cast<const short8v*>(er);
      const short8v v1 = *reinterpret_cast<const short8v*>(er + 8);
#pragma unroll
      for (int u = 0; u < 8; ++u) {
        av[u] += bf2f((unsigned short)v0[u]);
        av[8 + u] += bf2f((unsigned short)v1[u]);
      }
    }
    short8v o0, o1;
#pragma unroll
    for (int u = 0; u < 8; ++u) {
      o0[u] = (short)f2bf(av[u]);
      o1[u] = (short)f2bf(av[8 + u]);
    }
    const int c0 = 32 + sub * 2;
    *reinterpret_cast<short8v*>(A + ((i * 768 + c0 * 16) ^ ((i & 7) << 4))) = o0;
    *reinterpret_cast<short8v*>(A + ((i * 768 + (c0 + 1) * 16) ^ ((i & 7) << 4))) = o1;
  }
  __syncthreads();

  const int w = t >> 6, l = t & 63, lr = l & 15, lg = l >> 4;
  const int sw = (lr & 7) << 4;
  const int row0 = lr, row1 = 16 + lr;

  f32x4 acc[2][2];
#pragma unroll
  for (int mt = 0; mt < 2; ++mt)
#pragma unroll
    for (int q = 0; q < 2; ++q)
#pragma unroll
      for (int r = 0; r < 4; ++r) acc[mt][q][r] = 0.f;
#pragma unroll
  for (int kt = 0; kt < 12; ++kt) {
    const short8v a0 = *reinterpret_cast<const short8v*>(
        A + ((row0 * 768 + kt * 64 + lg * 16) ^ sw));
    const short8v a1 = *reinterpret_cast<const short8v*>(
        A + ((row1 * 768 + kt * 64 + lg * 16) ^ sw));
#pragma unroll
    for (int q = 0; q < 2; ++q) {
      const short8v bq = *reinterpret_cast<const short8v*>(
          wp + (((size_t)(kt * 8 + 2 * w + q) * 64 + l) << 3));
      acc[0][q] = __builtin_amdgcn_mfma_f32_16x16x32_bf16(a0, bq, acc[0][q], 0, 0, 0);
      acc[1][q] = __builtin_amdgcn_mfma_f32_16x16x32_bf16(a1, bq, acc[1][q], 0, 0, 0);
    }
  }
#pragma unroll
  for (int q = 0; q < 2; ++q) {
    const int col = (2 * w + q) * 16 + lr;
    const float bias = b[col];
#pragma unroll
    for (int mt = 0; mt < 2; ++mt)
#pragma unroll
      for (int r = 0; r < 4; ++r) {
        const int row = mt * 16 + lg * 4 + r;
        const float v = acc[mt][q][r] + bias;
        if (OUTF)
          ((float*)outp)[(size_t)(n0 + row) * DF + col] = v;
        else
          ((unsigned short*)outp)[(size_t)(n0 + row) * DF + col] = f2bf(v);
      }
  }

  if constexpr (PART) {
    __syncthreads();   // all MFMA reads of A done
#pragma unroll
    for (int q = 0; q < 2; ++q) {
      const int col = (2 * w + q) * 16 + lr;
      const float bias = b[col];
#pragma unroll
      for (int mt = 0; mt < 2; ++mt)
#pragma unroll
        for (int r = 0; r < 4; ++r) {
          const int row = mt * 16 + lg * 4 + r;
          *reinterpret_cast<unsigned short*>(
              A + ((row * 768 + 256 + col * 2) ^ ((row & 7) << 4))) =
              f2bf(acc[mt][q][r] + bias);
        }
    }
    __syncthreads();
    f32x4 aD[2][4], aSv[2][4];
#pragma unroll
    for (int mt = 0; mt < 2; ++mt)
#pragma unroll
      for (int q = 0; q < 4; ++q)
#pragma unroll
        for (int r = 0; r < 4; ++r) { aD[mt][q][r] = 0.f; aSv[mt][q][r] = 0.f; }
    const int r0p = lr * 768 + lg * 16, r1p = (16 + lr) * 768 + lg * 16;
#pragma unroll
    for (int kt = 0; kt < 8; ++kt) {
      const short8v a0 = *reinterpret_cast<const short8v*>(A + ((r0p + kt * 64) ^ sw));
      const short8v a1 = *reinterpret_cast<const short8v*>(A + ((r1p + kt * 64) ^ sw));
#pragma unroll
      for (int q = 0; q < 4; ++q) {
        const size_t bi = (((size_t)(kt * 16 + 4 * w + q) * 64 + l) << 3);
        const short8v bD = *reinterpret_cast<const short8v*>(wpd + bi);
        const short8v bSv = *reinterpret_cast<const short8v*>(wps + bi);
        aD[0][q] = __builtin_amdgcn_mfma_f32_16x16x32_bf16(a0, bD, aD[0][q], 0, 0, 0);
        aD[1][q] = __builtin_amdgcn_mfma_f32_16x16x32_bf16(a1, bD, aD[1][q], 0, 0, 0);
        aSv[0][q] = __builtin_amdgcn_mfma_f32_16x16x32_bf16(a0, bSv, aSv[0][q], 0, 0, 0);
        aSv[1][q] = __builtin_amdgcn_mfma_f32_16x16x32_bf16(a1, bSv, aSv[1][q], 0, 0, 0);
      }
    }
#pragma unroll
    for (int q = 0; q < 4; ++q) {
      const int col = (4 * w + q) * 16 + lr;
#pragma unroll
      for (int mt = 0; mt < 2; ++mt)
#pragma unroll
        for (int r = 0; r < 4; ++r) {
          const int row = mt * 16 + lg * 4 + r;
          PDo[(size_t)(n0 + row) * HH + col] = f2bf(aD[mt][q][r]);
          PSo[(size_t)(n0 + row) * HH + col] = f2bf(aSv[mt][q][r]);
        }
    }
  }

  if constexpr (HEADS) {
    __syncthreads();   // all MFMA reads of A done
    // A layout: [0,8192) nf tile bf16 ([32][128], stride 256B, swizzled);
    // [8192,16384) hid bf16; [16384,17408) part f32; [17408,21760) cw2 bf16.
    unsigned short* cw2b = reinterpret_cast<unsigned short*>(A + 17408);
    for (int j = t; j < DF * TT; j += 256) cw2b[j] = f2bf(cw2[j]);
#pragma unroll
    for (int q = 0; q < 2; ++q) {
      const int col = (2 * w + q) * 16 + lr;
      const float bias = b[col];
#pragma unroll
      for (int mt = 0; mt < 2; ++mt)
#pragma unroll
        for (int r = 0; r < 4; ++r) {
          const int row = mt * 16 + lg * 4 + r;
          *reinterpret_cast<unsigned short*>(
              A + ((row * 256 + col * 2) ^ ((row & 7) << 4))) =
              f2bf(acc[mt][q][r] + bias);
        }
    }
    __syncthreads();

    // ===== head 1: scalar (nc) =====
    f32x4 ah[2][2];
#pragma unroll
    for (int mt = 0; mt < 2; ++mt)
#pragma unroll
      for (int q = 0; q < 2; ++q)
#pragma unroll
        for (int r = 0; r < 4; ++r) ah[mt][q][r] = 0.f;
#pragma unroll
    for (int kt = 0; kt < 4; ++kt) {
      const short8v a0 = *reinterpret_cast<const short8v*>(
          A + ((row0 * 256 + kt * 64 + lg * 16) ^ sw));
      const short8v a1 = *reinterpret_cast<const short8v*>(
          A + ((row1 * 256 + kt * 64 + lg * 16) ^ sw));
#pragma unroll
      for (int q = 0; q < 2; ++q) {
        const short8v bq = *reinterpret_cast<const short8v*>(
            wpn + (((size_t)(kt * 8 + 2 * w + q) * 64 + l) << 3));
        ah[0][q] = __builtin_amdgcn_mfma_f32_16x16x32_bf16(a0, bq, ah[0][q], 0, 0, 0);
        ah[1][q] = __builtin_amdgcn_mfma_f32_16x16x32_bf16(a1, bq, ah[1][q], 0, 0, 0);
      }
    }
    unsigned short* hid = reinterpret_cast<unsigned short*>(A + 8192);
#pragma unroll
    for (int q = 0; q < 2; ++q) {
      const int col = (2 * w + q) * 16 + lr;
      const float bias = nb1[col];
#pragma unroll
      for (int mt = 0; mt < 2; ++mt)
#pragma unroll
        for (int r = 0; r < 4; ++r) {
          const int row = mt * 16 + lg * 4 + r;
          hid[row * 128 + col] = f2bf(fmaxf(ah[mt][q][r] + bias, 0.f));
        }
    }
    __syncthreads();
    float* part = reinterpret_cast<float*>(A + 16384);
    {
      const int rr = t >> 3, kc = t & 7;
      float s = 0.f;
#pragma unroll
      for (int u = 0; u < 16; ++u)
        s = fmaf(bf2f(hid[rr * 128 + kc * 16 + u]), nw2[kc * 16 + u], s);
      part[rr * 8 + kc] = s;
    }
    __syncthreads();
    if (t < 32) {
      float s = nb2[0];
#pragma unroll
      for (int k = 0; k < 8; ++k) s += part[t * 8 + k];
      out_pn[n0 + t] = s;
    }
    __syncthreads();   // before hid overwrite

    // ===== head 2: class (cc) =====
    f32x4 ac2[2][2];
#pragma unroll
    for (int mt = 0; mt < 2; ++mt)
#pragma unroll
      for (int q = 0; q < 2; ++q)
#pragma unroll
        for (int r = 0; r < 4; ++r) ac2[mt][q][r] = 0.f;
#pragma unroll
    for (int kt = 0; kt < 4; ++kt) {
      const short8v a0 = *reinterpret_cast<const short8v*>(
          A + ((row0 * 256 + kt * 64 + lg * 16) ^ sw));
      const short8v a1 = *reinterpret_cast<const short8v*>(
          A + ((row1 * 256 + kt * 64 + lg * 16) ^ sw));
#pragma unroll
      for (int q = 0; q < 2; ++q) {
        const short8v bq = *reinterpret_cast<const short8v*>(
            wpc + (((size_t)(kt * 8 + 2 * w + q) * 64 + l) << 3));
        ac2[0][q] = __builtin_amdgcn_mfma_f32_16x16x32_bf16(a0, bq, ac2[0][q], 0, 0, 0);
        ac2[1][q] = __builtin_amdgcn_mfma_f32_16x16x32_bf16(a1, bq, ac2[1][q], 0, 0, 0);
      }
    }
#pragma unroll
    for (int q = 0; q < 2; ++q) {
      const int col = (2 * w + q) * 16 + lr;
      const float bias = cb1[col];
#pragma unroll
      for (int mt = 0; mt < 2; ++mt)
#pragma unroll
        for (int r = 0; r < 4; ++r) {
          const int row = mt * 16 + lg * 4 + r;
          hid[row * 128 + col] = f2bf(fmaxf(ac2[mt][q][r] + bias, 0.f));
        }
    }
    __syncthreads();
    for (int o = t; o < 32 * TT; o += 256) {
      const int rr = o / TT, c = o - TT * rr;
      float s = cb2[c];
      for (int k = 0; k < DF; ++k)
        s = fmaf(bf2f(hid[rr * 128 + k]), bf2f(cw2b[k * TT + c]), s);
      out_pc[(size_t)(n0 + rr) * TT + c] = s;
    }
  }
}

// ---------------------------------------------------------------------------
extern "C" void kernel_launch(void* const* d_in, const int* in_sizes, int n_in,
                              void* d_out, int out_size, void* d_ws,
                              size_t ws_size, hipStream_t stream) {
  (void)in_sizes; (void)n_in; (void)out_size; (void)ws_size;
  const float* x         = (const float*)d_in[0];
  const float* edge_attr = (const float*)d_in[1];
  const int*   edge_idx  = (const int*)d_in[2];
  const int*   node_ty   = (const int*)d_in[3];
  const float* ne_w1 = (const float*)d_in[4];
  const float* ne_b1 = (const float*)d_in[5];
  const float* ne_w2 = (const float*)d_in[6];
  const float* ne_b2 = (const float*)d_in[7];
  const float* ee_w1 = (const float*)d_in[8];
  const float* ee_b1 = (const float*)d_in[9];
  const float* ee_w2 = (const float*)d_in[10];
  const float* ee_b2 = (const float*)d_in[11];
  const float* me_w1 = (const float*)d_in[12];
  const float* me_b1 = (const float*)d_in[13];
  const float* me_w2 = (const float*)d_in[14];
  const float* me_b2 = (const float*)d_in[15];
  const float* mn_w1 = (const float*)d_in[16];
  const float* mn_b1 = (const float*)d_in[17];
  const float* ec_w1 = (const float*)d_in[18];
  const float* ec_b1 = (const float*)d_in[19];
  const float* ec_w2 = (const float*)d_in[20];
  const float* ec_b2 = (const float*)d_in[21];
  const float* nc_w1 = (const float*)d_in[22];
  const float* nc_b1 = (const float*)d_in[23];
  const float* nc_w2 = (const float*)d_in[24];
  const float* nc_b2 = (const float*)d_in[25];
  const float* cc_w1 = (const float*)d_in[26];
  const float* cc_b1 = (const float*)d_in[27];
  const float* cc_w2 = (const float*)d_in[28];
  const float* cc_b2 = (const float*)d_in[29];

  const int* srcv = edge_idx;
  const int* dstv = edge_idx + N_EDGES;

  // ---- workspace layout ----
  unsigned short* nf0b = (unsigned short*)d_ws;
  unsigned short* nf1b = nf0b + (size_t)N_NODES * DF;
  unsigned short* ef0p = nf1b + (size_t)N_NODES * DF;      // PERMUTED ef0
  unsigned short* ef1p = ef0p + (size_t)N_EDGES * DF;      // PERMUTED ef
  unsigned short* wmpD = ef1p + (size_t)N_EDGES * DF;      // W1 rows 0:256
  unsigned short* wmpS = wmpD + 256 * 256;                 // W1 rows 256:512
  unsigned short* wmeE = wmpS + 256 * 256;                 // W1 rows 512:768
  unsigned short* wme2 = wmeE + 256 * 256;                 // 256x128
  unsigned short* wmn  = wme2 + 256 * 128;                 // 384x128
  unsigned short* wne1 = wmn + 384 * 128;                  // 17 x 256x128
  unsigned short* wne2 = wne1 + (size_t)TT * 256 * 128;    // 17 x 128x128
  unsigned short* wee1 = wne2 + (size_t)TT * 128 * 128;    // 64x128
  unsigned short* wee2 = wee1 + 64 * 128;                  // 128x128
  unsigned short* wec  = wee2 + 128 * 128;
  unsigned short* wnc  = wec + 128 * 128;
  unsigned short* wcc  = wnc + 128 * 128;
  unsigned short* PD   = wcc + 128 * 128;                  // [N][256] bf16
  unsigned short* PS   = PD + (size_t)N_NODES * HH;        // [N][256] bf16
  int* cnt    = (int*)(PS + (size_t)N_NODES * HH);
  int* woff   = cnt + 32;
  int* bucket = woff + 32;                                 // NE_PAD_SLOTS ints
  int* deg    = bucket + NE_PAD_SLOTS;                     // N
  int* rs     = deg + N_NODES;                             // N + 1
  int* wo     = rs + N_NODES + 1;                          // N
  int* elist  = wo + N_NODES;                              // E
  int* ipos   = elist + N_EDGES;                           // E
  int* srcp   = ipos + N_EDGES;                            // E
  int* dstp   = srcp + N_EDGES;                            // E

  // ---- output layout ----
  float* out_pe = (float*)d_out;
  float* out_pn = out_pe + N_EDGES;
  float* out_pc = out_pn + N_NODES;
  float* out_nf = out_pc + (size_t)N_NODES * TT;
  float* out_ef = out_nf + (size_t)N_NODES * DF;

  // ---- single-dispatch weight packing ----
  PackPtrs P;
  P.s0 = me_w1;            P.d0 = wmpD;
  P.s1 = me_w1 + 256*256;  P.d1 = wmpS;
  P.s2 = me_w1 + 512*256;  P.d2 = wmeE;
  P.s3 = me_w2;            P.d3 = wme2;
  P.s4 = mn_w1;            P.d4 = wmn;
  P.s5 = ne_w1;            P.d5 = wne1;
  P.s6 = ne_w2;            P.d6 = wne2;
  P.s7 = ee_w1;            P.d7 = wee1;
  P.s8 = ee_w2;            P.d8 = wee2;
  P.s9 = ec_w1;            P.d9 = wec;
  P.s10 = nc_w1;           P.d10 = wnc;
  P.s11 = cc_w1;           P.d11 = wcc;
  k_pack_all<<<580, 256, 0, stream>>>(P);

  // ---- setup (bucketing + CSR by dst, merged) ----
  hipMemsetAsync(cnt, 0, 32 * sizeof(int), stream);
  hipMemsetAsync(deg, 0, N_NODES * sizeof(int), stream);
  hipMemsetAsync(bucket, 0xFF, NE_PAD_SLOTS * sizeof(int), stream);
  k_count_deg<<<(N_EDGES + 255) / 256, 256, 0, stream>>>(node_ty, dstv, cnt, deg);
  k_prefix_scan<<<1, 1024, 0, stream>>>(cnt, woff, deg, rs, wo);
  k_scatter_elist<<<(N_EDGES + 255) / 256, 256, 0, stream>>>(
      node_ty, srcv, dstv, woff, wo, bucket, elist, ipos, srcp, dstp);

  // ---- fused embeddings (+ step-1 PD/PS partials in node blocks) ----
  k_embed_fused<<<NB_NODE + N_EDGES / 32, 256, 0, stream>>>(
      x, bucket, node_ty, wne1, ne_b1, wne2, ne_b2, nf0b, wmpD, wmpS, PD, PS,
      edge_attr, ipos, wee1, ee_b1, wee2, ee_b2, ef0p);

  // ---- mp step 1 (nf = nf0, ef = ef0) ----
  k_edge_mlp_mfma<false, false><<<N_EDGES / 32, 256, 0, stream>>>(
      ef0p, ef0p, ef1p, nullptr, srcp, dstp, elist, wmeE, me_b1, wme2, me_b2,
      PD, PS, nullptr, nullptr, nullptr, nullptr, nullptr);
  k_node_update_mfma<false, true, false><<<N_NODES / 32, 256, 0, stream>>>(
      nf0b, nf0b, ef1p, rs, (void*)nf1b, wmn, mn_b1, wmpD, wmpS, PD, PS,
      nullptr, nullptr, nullptr, nullptr, nullptr, nullptr, nullptr, nullptr,
      nullptr, nullptr);
  // ---- mp step 2 (fused edge head -> out_pe) ----
  k_edge_mlp_mfma<false, true><<<N_EDGES / 32, 256, 0, stream>>>(
      ef0p, ef1p, ef1p, nullptr, srcp, dstp, elist, wmeE, me_b1, wme2, me_b2,
      PD, PS, wec, ec_b1, ec_w2, ec_b2, out_pe);
  k_node_update_mfma<false, true, false><<<N_NODES / 32, 256, 0, stream>>>(
      nf0b, nf1b, ef1p, rs, (void*)nf1b, wmn, mn_b1, wmpD, wmpS, PD, PS,
      nullptr, nullptr, nullptr, nullptr, nullptr, nullptr, nullptr, nullptr,
      nullptr, nullptr);
  // ---- mp step 3 (ef out + fused node heads) ----
  k_edge_mlp_mfma<true, false><<<N_EDGES / 32, 256, 0, stream>>>(
      ef0p, ef1p, ef1p, out_ef, srcp, dstp, elist, wmeE, me_b1, wme2, me_b2,
      PD, PS, nullptr, nullptr, nullptr, nullptr, nullptr);
  k_node_update_mfma<true, false, true><<<N_NODES / 32, 256, 0, stream>>>(
      nf0b, nf1b, ef1p, rs, (void*)out_nf, wmn, mn_b1, wmpD, wmpS, PD, PS,
      wnc, nc_b1, nc_w2, nc_b2, wcc, cc_b1, cc_w2, cc_b2, out_pn, out_pc);
}